// Round 1
// baseline (1004.725 us; speedup 1.0000x reference)
//
#include <hip/hip_runtime.h>
#include <math.h>

#define EPSF 1e-5f

// problem sizes
#define BB 2
#define NN 6
#define KPIX 1680      // 28*60
#define DD 128
#define QQ 1024        // 32*32
#define HEADS 4
#define DHEAD 32
#define SPLIT 2
#define KCHUNK (KPIX/SPLIT)   // 840
#define TK 40
#define NTILE (KCHUNK/TK)     // 21
#define NQT 32                // 1024/32
#define NPART (NN*SPLIT)      // 12

__device__ __forceinline__ float blk_sum128(float v, float* s2, int t) {
#pragma unroll
  for (int off = 32; off > 0; off >>= 1) v += __shfl_down(v, off, 64);
  if ((t & 63) == 0) s2[t >> 6] = v;
  __syncthreads();
  float r = s2[0] + s2[1];
  __syncthreads();
  return r;
}

// --- camera-center embedding: c_embed[bn][o] = sum_c cam_w[o][c] * E_inv[bn][c][3]
__global__ void ce_kernel(const float* __restrict__ cam_w, const float* __restrict__ E_inv,
                          float* __restrict__ c_embed) {
  int bn = blockIdx.x; int t = threadIdx.x;
  const float* E = E_inv + bn * 16;
  float s = cam_w[t*4+0]*E[3] + cam_w[t*4+1]*E[7] + cam_w[t*4+2]*E[11] + cam_w[t*4+3]*E[15];
  c_embed[bn*128 + t] = s;
}

// --- per image pixel: img_embed + BN/ReLU/conv (fp,fl), fused K-LN+proj, V-LN+proj
__global__ __launch_bounds__(128) void kv_kernel(
    const float* __restrict__ feature, const float* __restrict__ I_inv,
    const float* __restrict__ E_inv, const float* __restrict__ image_plane,
    const float* __restrict__ c_embed, const float* __restrict__ img_w,
    const float* __restrict__ fp_bn_g, const float* __restrict__ fp_bn_b,
    const float* __restrict__ fp_bn_m, const float* __restrict__ fp_bn_v,
    const float* __restrict__ fp_w,
    const float* __restrict__ fl_bn_g, const float* __restrict__ fl_bn_b,
    const float* __restrict__ fl_bn_m, const float* __restrict__ fl_bn_v,
    const float* __restrict__ fl_w,
    const float* __restrict__ k_ln_g, const float* __restrict__ k_ln_b,
    const float* __restrict__ k_w, const float* __restrict__ k_b,
    const float* __restrict__ v_ln_g, const float* __restrict__ v_ln_b,
    const float* __restrict__ v_w, const float* __restrict__ v_b,
    float* __restrict__ kh, float* __restrict__ vh)
{
  int blk = blockIdx.x;
  int bn = blk / KPIX, k = blk % KPIX;
  int t = threadIdx.x;
  __shared__ float s_fp[128], s_fl[128], s_vec[128], s_red[2];

  const float* Ii = I_inv + bn*9;
  const float* Ei = E_inv + bn*16;
  float px = image_plane[k], py = image_plane[KPIX + k], pz = image_plane[2*KPIX + k];
  float c0 = Ii[0]*px + Ii[1]*py + Ii[2]*pz;
  float c1 = Ii[3]*px + Ii[4]*py + Ii[5]*pz;
  float c2 = Ii[6]*px + Ii[7]*py + Ii[8]*pz;
  float d0 = Ei[0]*c0 + Ei[1]*c1 + Ei[2]*c2  + Ei[3];
  float d1 = Ei[4]*c0 + Ei[5]*c1 + Ei[6]*c2  + Ei[7];
  float d2 = Ei[8]*c0 + Ei[9]*c1 + Ei[10]*c2 + Ei[11];
  float d3 = Ei[12]*c0 + Ei[13]*c1 + Ei[14]*c2 + Ei[15];
  float de = img_w[t*4+0]*d0 + img_w[t*4+1]*d1 + img_w[t*4+2]*d2 + img_w[t*4+3]*d3;
  float ime = de - c_embed[bn*128 + t];
  float ss = blk_sum128(ime*ime, s_red, t);
  ime = ime / (sqrtf(ss) + 1e-7f);

  float f = feature[((size_t)(bn*128 + t))*KPIX + k];
  float thp = (f - fp_bn_m[t]) * (fp_bn_g[t] / sqrtf(fp_bn_v[t] + EPSF)) + fp_bn_b[t];
  float thl = (f - fl_bn_m[t]) * (fl_bn_g[t] / sqrtf(fl_bn_v[t] + EPSF)) + fl_bn_b[t];
  s_fp[t] = fmaxf(thp, 0.f);
  s_fl[t] = fmaxf(thl, 0.f);
  __syncthreads();

  float keyv = ime, valv = 0.f;
#pragma unroll 8
  for (int c = 0; c < 128; ++c) {
    keyv += fp_w[t*128 + c] * s_fp[c];
    valv += fl_w[t*128 + c] * s_fl[c];
  }

  // K: LN + proj
  float mu = blk_sum128(keyv, s_red, t) * (1.f/128.f);
  float dv = keyv - mu;
  float var = blk_sum128(dv*dv, s_red, t) * (1.f/128.f);
  float kn = dv * rsqrtf(var + EPSF) * k_ln_g[t] + k_ln_b[t];
  s_vec[t] = kn;
  __syncthreads();
  float kout = k_b[t];
#pragma unroll 8
  for (int o = 0; o < 128; ++o) kout += s_vec[o] * k_w[o*128 + t];
  kh[((size_t)bn*KPIX + k)*128 + t] = kout;
  __syncthreads();

  // V: LN + proj
  mu = blk_sum128(valv, s_red, t) * (1.f/128.f);
  dv = valv - mu;
  var = blk_sum128(dv*dv, s_red, t) * (1.f/128.f);
  float vn = dv * rsqrtf(var + EPSF) * v_ln_g[t] + v_ln_b[t];
  s_vec[t] = vn;
  __syncthreads();
  float vout = v_b[t];
#pragma unroll 8
  for (int o = 0; o < 128; ++o) vout += s_vec[o] * v_w[o*128 + t];
  vh[((size_t)bn*KPIX + k)*128 + t] = vout;
}

// --- per BEV query: bev embed + x, LN, q-proj
__global__ __launch_bounds__(128) void q_kernel(
    const float* __restrict__ x, const float* __restrict__ bev_grid,
    const float* __restrict__ bev_w, const float* __restrict__ bev_b,
    const float* __restrict__ c_embed,
    const float* __restrict__ q_ln_g, const float* __restrict__ q_ln_b,
    const float* __restrict__ q_w, const float* __restrict__ q_b,
    float* __restrict__ qh)
{
  int blk = blockIdx.x;
  int bn = blk / QQ, qi = blk % QQ;
  int b = bn / NN;
  int t = threadIdx.x;
  __shared__ float s_vec[128], s_red[2];
  float gx = bev_grid[qi], gy = bev_grid[QQ + qi];
  float we = bev_w[t*2+0]*gx + bev_w[t*2+1]*gy + bev_b[t];
  float be = we - c_embed[bn*128 + t];
  float ss = blk_sum128(be*be, s_red, t);
  be = be / (sqrtf(ss) + 1e-7f);
  float qv = be + x[((size_t)b*128 + t)*QQ + qi];
  float mu = blk_sum128(qv, s_red, t) * (1.f/128.f);
  float dv = qv - mu;
  float var = blk_sum128(dv*dv, s_red, t) * (1.f/128.f);
  float qn = dv * rsqrtf(var + EPSF) * q_ln_g[t] + q_ln_b[t];
  s_vec[t] = qn;
  __syncthreads();
  float qout = q_b[t];
#pragma unroll 8
  for (int o = 0; o < 128; ++o) qout += s_vec[o] * q_w[o*128 + t];
  qh[((size_t)bn*QQ + qi)*128 + t] = qout;
}

// --- flash attention partials: block = (b, qtile32, n, ksplit); thread = (head, q)
__global__ __launch_bounds__(128) void attn_kernel(
    const float* __restrict__ qh, const float* __restrict__ kh,
    const float* __restrict__ vh, float* __restrict__ part)
{
  int blk = blockIdx.x;
  int sp = blk % SPLIT; blk /= SPLIT;
  int n  = blk % NN;    blk /= NN;
  int qt = blk % NQT;   blk /= NQT;
  int b  = blk;
  int t = threadIdx.x;
  int m = t >> 5, ql = t & 31;
  int q = qt*32 + ql;

  __shared__ float klds[TK*128], vlds[TK*128];

  float qreg[32];
  const float* qp = qh + ((size_t)(b*NN+n)*QQ + q)*128 + m*32;
#pragma unroll
  for (int d = 0; d < 32; ++d) qreg[d] = qp[d];

  const float scale = 0.17677669529663687f; // 32^-0.5
  float mrun = -INFINITY, lrun = 0.f;
  float acc[32];
#pragma unroll
  for (int d = 0; d < 32; ++d) acc[d] = 0.f;

  size_t kvbase = ((size_t)(b*NN+n)*KPIX + sp*KCHUNK)*128;
  for (int tile = 0; tile < NTILE; ++tile) {
    const float* kp = kh + kvbase + (size_t)tile*TK*128;
    const float* vp = vh + kvbase + (size_t)tile*TK*128;
    for (int idx = t; idx < TK*128; idx += 128) {
      klds[idx] = kp[idx];
      vlds[idx] = vp[idx];
    }
    __syncthreads();
    for (int kk = 0; kk < TK; ++kk) {
      const float* kv = &klds[kk*128 + m*32];
      float s = 0.f;
#pragma unroll
      for (int d = 0; d < 32; ++d) s += qreg[d]*kv[d];
      s *= scale;
      if (s > mrun) {
        float corr = __expf(mrun - s);
        lrun *= corr;
#pragma unroll
        for (int d = 0; d < 32; ++d) acc[d] *= corr;
        mrun = s;
      }
      float p = __expf(s - mrun);
      lrun += p;
      const float* vv = &vlds[kk*128 + m*32];
#pragma unroll
      for (int d = 0; d < 32; ++d) acc[d] += p*vv[d];
    }
    __syncthreads();
  }
  size_t pb = (((size_t)(b*HEADS+m)*QQ + q)*NPART + (n*SPLIT+sp))*34;
  part[pb] = mrun; part[pb+1] = lrun;
#pragma unroll
  for (int d = 0; d < 32; ++d) part[pb+2+d] = acc[d];
}

// --- combine partials + proj + skip + preLN + MLP(gelu) + postLN + transposed store
__global__ __launch_bounds__(128) void epi_kernel(
    const float* __restrict__ part, const float* __restrict__ x,
    const float* __restrict__ proj_w, const float* __restrict__ proj_b,
    const float* __restrict__ pre_g, const float* __restrict__ pre_b,
    const float* __restrict__ mlp_w1, const float* __restrict__ mlp_b1,
    const float* __restrict__ mlp_w2, const float* __restrict__ mlp_b2,
    const float* __restrict__ post_g, const float* __restrict__ post_b,
    float* __restrict__ out)
{
  int blk = blockIdx.x;
  int b = blk / QQ, q = blk % QQ;
  int t = threadIdx.x;
  int d = t & 31, m = t >> 5;
  __shared__ float s_a[128], s_z[128], s_h[256], s_red[2];

  const float* P = part + (((size_t)(b*HEADS+m)*QQ + q)*NPART)*34;
  float M = -INFINITY;
#pragma unroll
  for (int j = 0; j < NPART; ++j) M = fmaxf(M, P[j*34]);
  float lt = 0.f, av = 0.f;
#pragma unroll
  for (int j = 0; j < NPART; ++j) {
    float w = __expf(P[j*34] - M);
    lt += P[j*34+1]*w;
    av += P[j*34+2+d]*w;
  }
  s_a[t] = av / lt;
  __syncthreads();

  float z = proj_b[t] + x[((size_t)b*128 + t)*QQ + q];
#pragma unroll 8
  for (int i = 0; i < 128; ++i) z += s_a[i]*proj_w[i*128 + t];
  float mu = blk_sum128(z, s_red, t)*(1.f/128.f);
  float dv = z - mu;
  float var = blk_sum128(dv*dv, s_red, t)*(1.f/128.f);
  float zn = dv*rsqrtf(var + EPSF)*pre_g[t] + pre_b[t];
  s_z[t] = zn;
  __syncthreads();
  float h0 = mlp_b1[t], h1 = mlp_b1[t+128];
#pragma unroll 8
  for (int o = 0; o < 128; ++o) {
    float zo = s_z[o];
    h0 += zo*mlp_w1[o*256 + t];
    h1 += zo*mlp_w1[o*256 + t + 128];
  }
  s_h[t]     = 0.5f*h0*(1.f + erff(h0*0.7071067811865476f));
  s_h[t+128] = 0.5f*h1*(1.f + erff(h1*0.7071067811865476f));
  __syncthreads();
  float mo = mlp_b2[t];
#pragma unroll 8
  for (int h = 0; h < 256; ++h) mo += s_h[h]*mlp_w2[h*128 + t];
  float z2 = zn + mo;
  mu = blk_sum128(z2, s_red, t)*(1.f/128.f);
  dv = z2 - mu;
  var = blk_sum128(dv*dv, s_red, t)*(1.f/128.f);
  float o2 = dv*rsqrtf(var + EPSF)*post_g[t] + post_b[t];
  out[((size_t)b*128 + t)*QQ + q] = o2;
}

extern "C" void kernel_launch(void* const* d_in, const int* in_sizes, int n_in,
                              void* d_out, int out_size, void* d_ws, size_t ws_size,
                              hipStream_t stream) {
  const float* x           = (const float*)d_in[0];
  const float* feature     = (const float*)d_in[1];
  const float* I_inv       = (const float*)d_in[2];
  const float* E_inv       = (const float*)d_in[3];
  const float* bev_grid    = (const float*)d_in[4];
  const float* image_plane = (const float*)d_in[5];
  const float* fl_bn_g = (const float*)d_in[6];
  const float* fl_bn_b = (const float*)d_in[7];
  const float* fl_bn_m = (const float*)d_in[8];
  const float* fl_bn_v = (const float*)d_in[9];
  const float* fl_w    = (const float*)d_in[10];
  const float* fp_bn_g = (const float*)d_in[11];
  const float* fp_bn_b = (const float*)d_in[12];
  const float* fp_bn_m = (const float*)d_in[13];
  const float* fp_bn_v = (const float*)d_in[14];
  const float* fp_w    = (const float*)d_in[15];
  const float* bev_w   = (const float*)d_in[16];
  const float* bev_b   = (const float*)d_in[17];
  const float* img_w   = (const float*)d_in[18];
  const float* cam_w   = (const float*)d_in[19];
  const float* q_ln_g  = (const float*)d_in[20];
  const float* q_ln_b  = (const float*)d_in[21];
  const float* q_w     = (const float*)d_in[22];
  const float* q_b     = (const float*)d_in[23];
  const float* k_ln_g  = (const float*)d_in[24];
  const float* k_ln_b  = (const float*)d_in[25];
  const float* k_w     = (const float*)d_in[26];
  const float* k_b     = (const float*)d_in[27];
  const float* v_ln_g  = (const float*)d_in[28];
  const float* v_ln_b  = (const float*)d_in[29];
  const float* v_w     = (const float*)d_in[30];
  const float* v_b     = (const float*)d_in[31];
  const float* proj_w  = (const float*)d_in[32];
  const float* proj_b  = (const float*)d_in[33];
  const float* pre_g   = (const float*)d_in[34];
  const float* pre_b   = (const float*)d_in[35];
  const float* mlp_w1  = (const float*)d_in[36];
  const float* mlp_b1  = (const float*)d_in[37];
  const float* mlp_w2  = (const float*)d_in[38];
  const float* mlp_b2  = (const float*)d_in[39];
  const float* post_g  = (const float*)d_in[40];
  const float* post_b  = (const float*)d_in[41];

  float* ws = (float*)d_ws;
  float* c_embed = ws;                                  // 12*128            = 1536
  float* qh      = c_embed + 1536;                      // 12*1024*128       = 1572864
  float* kh      = qh + 12*1024*128;                    // 12*1680*128       = 2580480
  float* vh      = kh + 12*1680*128;                    // 12*1680*128       = 2580480
  float* part    = vh + 12*1680*128;                    // 2*4*1024*12*34    = 3342336
  float* out     = (float*)d_out;

  hipLaunchKernelGGL(ce_kernel, dim3(BB*NN), dim3(128), 0, stream, cam_w, E_inv, c_embed);
  hipLaunchKernelGGL(kv_kernel, dim3(BB*NN*KPIX), dim3(128), 0, stream,
                     feature, I_inv, E_inv, image_plane, c_embed, img_w,
                     fp_bn_g, fp_bn_b, fp_bn_m, fp_bn_v, fp_w,
                     fl_bn_g, fl_bn_b, fl_bn_m, fl_bn_v, fl_w,
                     k_ln_g, k_ln_b, k_w, k_b,
                     v_ln_g, v_ln_b, v_w, v_b,
                     kh, vh);
  hipLaunchKernelGGL(q_kernel, dim3(BB*NN*QQ), dim3(128), 0, stream,
                     x, bev_grid, bev_w, bev_b, c_embed,
                     q_ln_g, q_ln_b, q_w, q_b, qh);
  hipLaunchKernelGGL(attn_kernel, dim3(BB*NQT*NN*SPLIT), dim3(128), 0, stream,
                     qh, kh, vh, part);
  hipLaunchKernelGGL(epi_kernel, dim3(BB*QQ), dim3(128), 0, stream,
                     part, x, proj_w, proj_b, pre_g, pre_b,
                     mlp_w1, mlp_b1, mlp_w2, mlp_b2, post_g, post_b, out);
}

// Round 2
// 375.375 us; speedup vs baseline: 2.6766x; 2.6766x over previous
//
#include <hip/hip_runtime.h>
#include <math.h>

#define EPSF 1e-5f

// problem sizes
#define BB 2
#define NN 6
#define KPIX 1680      // 28*60
#define DD 128
#define QQ 1024        // 32*32
#define HEADS 4
#define DHEAD 32
#define TK 35          // kv tile for attn LDS staging (divides 210/280/420/840)

__device__ __forceinline__ float wred32(float v) {
#pragma unroll
  for (int off = 16; off > 0; off >>= 1) v += __shfl_xor(v, off, 32);
  return v;
}

__device__ __forceinline__ float blk_sum128(float v, float* s2, int t) {
#pragma unroll
  for (int off = 32; off > 0; off >>= 1) v += __shfl_down(v, off, 64);
  if ((t & 63) == 0) s2[t >> 6] = v;
  __syncthreads();
  float r = s2[0] + s2[1];
  __syncthreads();
  return r;
}

// --- camera-center embedding: c_embed[bn][o] = sum_c cam_w[o][c] * E_inv[bn][c][3]
__global__ void ce_kernel(const float* __restrict__ cam_w, const float* __restrict__ E_inv,
                          float* __restrict__ c_embed) {
  int bn = blockIdx.x; int t = threadIdx.x;
  const float* E = E_inv + bn * 16;
  float s = cam_w[t*4+0]*E[3] + cam_w[t*4+1]*E[7] + cam_w[t*4+2]*E[11] + cam_w[t*4+3]*E[15];
  c_embed[bn*128 + t] = s;
}

// --- 8 pixels per block: img_embed + BN/ReLU/conv (fp,fl), K-LN+proj, V-LN+proj
__global__ __launch_bounds__(256) void kv_kernel(
    const float* __restrict__ feature, const float* __restrict__ I_inv,
    const float* __restrict__ E_inv, const float* __restrict__ image_plane,
    const float* __restrict__ c_embed, const float* __restrict__ img_w,
    const float* __restrict__ fp_bn_g, const float* __restrict__ fp_bn_b,
    const float* __restrict__ fp_bn_m, const float* __restrict__ fp_bn_v,
    const float* __restrict__ fp_w,
    const float* __restrict__ fl_bn_g, const float* __restrict__ fl_bn_b,
    const float* __restrict__ fl_bn_m, const float* __restrict__ fl_bn_v,
    const float* __restrict__ fl_w,
    const float* __restrict__ k_ln_g, const float* __restrict__ k_ln_b,
    const float* __restrict__ k_w, const float* __restrict__ k_b,
    const float* __restrict__ v_ln_g, const float* __restrict__ v_ln_b,
    const float* __restrict__ v_w, const float* __restrict__ v_b,
    float* __restrict__ kh, float* __restrict__ vh)
{
  int blk = blockIdx.x;
  int bn = blk / (KPIX/8), kc = blk % (KPIX/8);
  int k0 = kc * 8;
  int t = threadIdx.x;
  __shared__ float s_fp[1024], s_fl[1024], s_ime[1024], s_k[1024], s_v[1024];

  // ---- phase A: per-pixel ray embed + normalize, BN+ReLU of feature ----
  {
    int l = t & 31, p = t >> 5;
    int k = k0 + p;
    const float* Ii = I_inv + bn*9;
    const float* Ei = E_inv + bn*16;
    float px = image_plane[k], py = image_plane[KPIX + k], pz = image_plane[2*KPIX + k];
    float c0 = Ii[0]*px + Ii[1]*py + Ii[2]*pz;
    float c1 = Ii[3]*px + Ii[4]*py + Ii[5]*pz;
    float c2 = Ii[6]*px + Ii[7]*py + Ii[8]*pz;
    float d0 = Ei[0]*c0 + Ei[1]*c1 + Ei[2]*c2  + Ei[3];
    float d1 = Ei[4]*c0 + Ei[5]*c1 + Ei[6]*c2  + Ei[7];
    float d2 = Ei[8]*c0 + Ei[9]*c1 + Ei[10]*c2 + Ei[11];
    float d3 = Ei[12]*c0 + Ei[13]*c1 + Ei[14]*c2 + Ei[15];
    float imv[4]; float ss = 0.f;
#pragma unroll
    for (int j = 0; j < 4; ++j) {
      int o = l + 32*j;
      float de = img_w[o*4+0]*d0 + img_w[o*4+1]*d1 + img_w[o*4+2]*d2 + img_w[o*4+3]*d3;
      float ime = de - c_embed[bn*128 + o];
      imv[j] = ime; ss += ime*ime;
    }
    ss = wred32(ss);
    float rinv = 1.f/(sqrtf(ss) + 1e-7f);
#pragma unroll
    for (int j = 0; j < 4; ++j) {
      int o = l + 32*j;
      s_ime[o*8 + p] = imv[j]*rinv;
      float f = feature[((size_t)(bn*128 + o))*KPIX + k];
      float thp = (f - fp_bn_m[o]) * (fp_bn_g[o]*rsqrtf(fp_bn_v[o]+EPSF)) + fp_bn_b[o];
      float thl = (f - fl_bn_m[o]) * (fl_bn_g[o]*rsqrtf(fl_bn_v[o]+EPSF)) + fl_bn_b[o];
      s_fp[o*8 + p] = fmaxf(thp, 0.f);
      s_fl[o*8 + p] = fmaxf(thl, 0.f);
    }
  }
  __syncthreads();

  // ---- phase B: conv1x1 (fp -> key base, fl -> val base), 4 pixels per thread ----
  int oo = t & 127, h = t >> 7;
  {
    float ka0=0,ka1=0,ka2=0,ka3=0, va0=0,va1=0,va2=0,va3=0;
    const float* wp = fp_w + (size_t)oo*128;
    const float* wl = fl_w + (size_t)oo*128;
#pragma unroll 8
    for (int c = 0; c < 128; ++c) {
      float wfp = wp[c], wfl = wl[c];
      float4 afp = *(const float4*)&s_fp[c*8 + h*4];
      float4 afl = *(const float4*)&s_fl[c*8 + h*4];
      ka0 += wfp*afp.x; ka1 += wfp*afp.y; ka2 += wfp*afp.z; ka3 += wfp*afp.w;
      va0 += wfl*afl.x; va1 += wfl*afl.y; va2 += wfl*afl.z; va3 += wfl*afl.w;
    }
    float4 im4 = *(const float4*)&s_ime[oo*8 + h*4];
    ka0 += im4.x; ka1 += im4.y; ka2 += im4.z; ka3 += im4.w;
    *(float4*)&s_k[oo*8 + h*4] = make_float4(ka0,ka1,ka2,ka3);
    *(float4*)&s_v[oo*8 + h*4] = make_float4(va0,va1,va2,va3);
  }
  __syncthreads();

  // ---- phase C: LayerNorm (in place) for K and V vectors ----
  {
    int l = t & 31, p = t >> 5;
    float kj[4], vj[4];
    float s1k=0,s2k=0,s1v=0,s2v=0;
#pragma unroll
    for (int j = 0; j < 4; ++j) {
      int o = l + 32*j;
      float a = s_k[o*8 + p]; kj[j] = a; s1k += a; s2k += a*a;
      float bq = s_v[o*8 + p]; vj[j] = bq; s1v += bq; s2v += bq*bq;
    }
    s1k = wred32(s1k); s2k = wred32(s2k); s1v = wred32(s1v); s2v = wred32(s2v);
    float muk = s1k*(1.f/128.f), vark = s2k*(1.f/128.f) - muk*muk;
    float muv = s1v*(1.f/128.f), varv = s2v*(1.f/128.f) - muv*muv;
    float rsk = rsqrtf(vark + EPSF), rsv = rsqrtf(varv + EPSF);
#pragma unroll
    for (int j = 0; j < 4; ++j) {
      int o = l + 32*j;
      s_k[o*8 + p] = (kj[j]-muk)*rsk*k_ln_g[o] + k_ln_b[o];
      s_v[o*8 + p] = (vj[j]-muv)*rsv*v_ln_g[o] + v_ln_b[o];
    }
  }
  __syncthreads();

  // ---- phase D: K/V projection, 4 pixels per thread ----
  {
    float kb = k_b[oo], vb = v_b[oo];
    float k0a=kb,k1a=kb,k2a=kb,k3a=kb, v0a=vb,v1a=vb,v2a=vb,v3a=vb;
#pragma unroll 8
    for (int o2 = 0; o2 < 128; ++o2) {
      float wk = k_w[(size_t)o2*128 + oo];
      float wv = v_w[(size_t)o2*128 + oo];
      float4 ak = *(const float4*)&s_k[o2*8 + h*4];
      float4 av = *(const float4*)&s_v[o2*8 + h*4];
      k0a += wk*ak.x; k1a += wk*ak.y; k2a += wk*ak.z; k3a += wk*ak.w;
      v0a += wv*av.x; v1a += wv*av.y; v2a += wv*av.z; v3a += wv*av.w;
    }
    float ko[4] = {k0a,k1a,k2a,k3a}, vo[4] = {v0a,v1a,v2a,v3a};
#pragma unroll
    for (int pp = 0; pp < 4; ++pp) {
      size_t row = ((size_t)bn*KPIX + (k0 + h*4 + pp))*128;
      kh[row + oo] = ko[pp];
      vh[row + oo] = vo[pp];
    }
  }
}

// --- 8 queries per block: bev embed + x, LN, q-proj
__global__ __launch_bounds__(256) void q_kernel(
    const float* __restrict__ x, const float* __restrict__ bev_grid,
    const float* __restrict__ bev_w, const float* __restrict__ bev_b,
    const float* __restrict__ c_embed,
    const float* __restrict__ q_ln_g, const float* __restrict__ q_ln_b,
    const float* __restrict__ q_w, const float* __restrict__ q_b,
    float* __restrict__ qh)
{
  int blk = blockIdx.x;
  int bn = blk >> 7, qc = blk & 127;
  int q0 = qc * 8;
  int b = bn / NN;
  int t = threadIdx.x;
  __shared__ float s_q[1024];

  {
    int l = t & 31, p = t >> 5;
    int qi = q0 + p;
    float gx = bev_grid[qi], gy = bev_grid[QQ + qi];
    float vj[4]; float ss = 0.f;
#pragma unroll
    for (int j = 0; j < 4; ++j) {
      int o = l + 32*j;
      float we = bev_w[o*2+0]*gx + bev_w[o*2+1]*gy + bev_b[o];
      float be = we - c_embed[bn*128 + o];
      vj[j] = be; ss += be*be;
    }
    ss = wred32(ss);
    float rinv = 1.f/(sqrtf(ss) + 1e-7f);
    float s1 = 0.f, s2 = 0.f;
#pragma unroll
    for (int j = 0; j < 4; ++j) {
      int o = l + 32*j;
      float qv = vj[j]*rinv + x[((size_t)(b*128 + o))*QQ + qi];
      vj[j] = qv; s1 += qv; s2 += qv*qv;
    }
    s1 = wred32(s1); s2 = wred32(s2);
    float mu = s1*(1.f/128.f), var = s2*(1.f/128.f) - mu*mu;
    float rs = rsqrtf(var + EPSF);
#pragma unroll
    for (int j = 0; j < 4; ++j) {
      int o = l + 32*j;
      s_q[o*8 + p] = (vj[j]-mu)*rs*q_ln_g[o] + q_ln_b[o];
    }
  }
  __syncthreads();

  {
    int oo = t & 127, h = t >> 7;
    float qb = q_b[oo];
    float a0=qb,a1=qb,a2=qb,a3=qb;
#pragma unroll 8
    for (int o2 = 0; o2 < 128; ++o2) {
      float w = q_w[(size_t)o2*128 + oo];
      float4 a = *(const float4*)&s_q[o2*8 + h*4];
      a0 += w*a.x; a1 += w*a.y; a2 += w*a.z; a3 += w*a.w;
    }
    float qo[4] = {a0,a1,a2,a3};
#pragma unroll
    for (int pp = 0; pp < 4; ++pp)
      qh[((size_t)bn*QQ + (q0 + h*4 + pp))*128 + oo] = qo[pp];
  }
}

// --- flash attention partials: block = (b, qtile64, n, ksplit); 256 thr = (head, q)
__global__ __launch_bounds__(256, 4) void attn_kernel(
    const float* __restrict__ qh, const float* __restrict__ kh,
    const float* __restrict__ vh, float* __restrict__ part,
    int split, int kchunk, int ntile, int npart)
{
  int blk = blockIdx.x;
  int sp = blk % split; blk /= split;
  int n  = blk % NN;    blk /= NN;
  int qt = blk % 16;    blk /= 16;
  int b  = blk;
  int t = threadIdx.x;
  int m = t >> 6, ql = t & 63;
  int q = qt*64 + ql;

  __shared__ float4 kbuf4[TK*32], vbuf4[TK*32];
  const float* klds = (const float*)kbuf4;
  const float* vlds = (const float*)vbuf4;

  float qreg[32];
  const float* qp = qh + ((size_t)(b*NN+n)*QQ + q)*128 + m*32;
#pragma unroll
  for (int d = 0; d < 32; ++d) qreg[d] = qp[d];

  const float scale = 0.17677669529663687f; // 32^-0.5
  float mrun = -INFINITY, lrun = 0.f;
  float acc[32];
#pragma unroll
  for (int d = 0; d < 32; ++d) acc[d] = 0.f;

  size_t kvbase = ((size_t)(b*NN+n)*KPIX + (size_t)sp*kchunk)*128;
  for (int tile = 0; tile < ntile; ++tile) {
    const float4* kp4 = (const float4*)(kh + kvbase + (size_t)tile*TK*128);
    const float4* vp4 = (const float4*)(vh + kvbase + (size_t)tile*TK*128);
    for (int i = t; i < TK*32; i += 256) {
      kbuf4[i] = kp4[i];
      vbuf4[i] = vp4[i];
    }
    __syncthreads();
    const float* kbase = klds + m*32;
    const float* vbase = vlds + m*32;
    for (int kk = 0; kk < TK; ++kk) {
      const float* kv = kbase + kk*128;
      float s = 0.f;
#pragma unroll
      for (int d = 0; d < 32; ++d) s += qreg[d]*kv[d];
      s *= scale;
      if (s > mrun + 8.f) {   // defer-max: fires ~never after key 0
        float corr = __expf(mrun - s);
        lrun *= corr;
#pragma unroll
        for (int d = 0; d < 32; ++d) acc[d] *= corr;
        mrun = s;
      }
      float p = __expf(s - mrun);
      lrun += p;
      const float* vv = vbase + kk*128;
#pragma unroll
      for (int d = 0; d < 32; ++d) acc[d] += p*vv[d];
    }
    __syncthreads();
  }
  size_t pb = (((size_t)(b*HEADS+m)*QQ + q)*npart + (n*split+sp))*34;
  part[pb] = mrun; part[pb+1] = lrun;
#pragma unroll
  for (int d = 0; d < 32; ++d) part[pb+2+d] = acc[d];
}

// --- combine partials + proj + skip + preLN + MLP(gelu) + postLN + transposed store
__global__ __launch_bounds__(128) void epi_kernel(
    const float* __restrict__ part, const float* __restrict__ x,
    const float* __restrict__ proj_w, const float* __restrict__ proj_b,
    const float* __restrict__ pre_g, const float* __restrict__ pre_b,
    const float* __restrict__ mlp_w1, const float* __restrict__ mlp_b1,
    const float* __restrict__ mlp_w2, const float* __restrict__ mlp_b2,
    const float* __restrict__ post_g, const float* __restrict__ post_b,
    float* __restrict__ out, int npart)
{
  int blk = blockIdx.x;
  int b = blk / QQ, q = blk % QQ;
  int t = threadIdx.x;
  int d = t & 31, m = t >> 5;
  __shared__ float s_a[128], s_z[128], s_h[256], s_red[2];

  const float* P = part + (((size_t)(b*HEADS+m)*QQ + q)*npart)*34;
  float M = -INFINITY;
  for (int j = 0; j < npart; ++j) M = fmaxf(M, P[j*34]);
  float lt = 0.f, av = 0.f;
  for (int j = 0; j < npart; ++j) {
    float w = __expf(P[j*34] - M);
    lt += P[j*34+1]*w;
    av += P[j*34+2+d]*w;
  }
  s_a[t] = av / lt;
  __syncthreads();

  float z = proj_b[t] + x[((size_t)b*128 + t)*QQ + q];
#pragma unroll 8
  for (int i = 0; i < 128; ++i) z += s_a[i]*proj_w[i*128 + t];
  float mu = blk_sum128(z, s_red, t)*(1.f/128.f);
  float dv = z - mu;
  float var = blk_sum128(dv*dv, s_red, t)*(1.f/128.f);
  float zn = dv*rsqrtf(var + EPSF)*pre_g[t] + pre_b[t];
  s_z[t] = zn;
  __syncthreads();
  float h0 = mlp_b1[t], h1 = mlp_b1[t+128];
#pragma unroll 8
  for (int o = 0; o < 128; ++o) {
    float zo = s_z[o];
    h0 += zo*mlp_w1[o*256 + t];
    h1 += zo*mlp_w1[o*256 + t + 128];
  }
  s_h[t]     = 0.5f*h0*(1.f + erff(h0*0.7071067811865476f));
  s_h[t+128] = 0.5f*h1*(1.f + erff(h1*0.7071067811865476f));
  __syncthreads();
  float mo = mlp_b2[t];
#pragma unroll 8
  for (int hh = 0; hh < 256; ++hh) mo += s_h[hh]*mlp_w2[hh*128 + t];
  float z2 = zn + mo;
  mu = blk_sum128(z2, s_red, t)*(1.f/128.f);
  dv = z2 - mu;
  var = blk_sum128(dv*dv, s_red, t)*(1.f/128.f);
  float o2 = dv*rsqrtf(var + EPSF)*post_g[t] + post_b[t];
  out[((size_t)b*128 + t)*QQ + q] = o2;
}

extern "C" void kernel_launch(void* const* d_in, const int* in_sizes, int n_in,
                              void* d_out, int out_size, void* d_ws, size_t ws_size,
                              hipStream_t stream) {
  const float* x           = (const float*)d_in[0];
  const float* feature     = (const float*)d_in[1];
  const float* I_inv       = (const float*)d_in[2];
  const float* E_inv       = (const float*)d_in[3];
  const float* bev_grid    = (const float*)d_in[4];
  const float* image_plane = (const float*)d_in[5];
  const float* fl_bn_g = (const float*)d_in[6];
  const float* fl_bn_b = (const float*)d_in[7];
  const float* fl_bn_m = (const float*)d_in[8];
  const float* fl_bn_v = (const float*)d_in[9];
  const float* fl_w    = (const float*)d_in[10];
  const float* fp_bn_g = (const float*)d_in[11];
  const float* fp_bn_b = (const float*)d_in[12];
  const float* fp_bn_m = (const float*)d_in[13];
  const float* fp_bn_v = (const float*)d_in[14];
  const float* fp_w    = (const float*)d_in[15];
  const float* bev_w   = (const float*)d_in[16];
  const float* bev_b   = (const float*)d_in[17];
  const float* img_w   = (const float*)d_in[18];
  const float* cam_w   = (const float*)d_in[19];
  const float* q_ln_g  = (const float*)d_in[20];
  const float* q_ln_b  = (const float*)d_in[21];
  const float* q_w     = (const float*)d_in[22];
  const float* q_b     = (const float*)d_in[23];
  const float* k_ln_g  = (const float*)d_in[24];
  const float* k_ln_b  = (const float*)d_in[25];
  const float* k_w     = (const float*)d_in[26];
  const float* k_b     = (const float*)d_in[27];
  const float* v_ln_g  = (const float*)d_in[28];
  const float* v_ln_b  = (const float*)d_in[29];
  const float* v_w     = (const float*)d_in[30];
  const float* v_b     = (const float*)d_in[31];
  const float* proj_w  = (const float*)d_in[32];
  const float* proj_b  = (const float*)d_in[33];
  const float* pre_g   = (const float*)d_in[34];
  const float* pre_b   = (const float*)d_in[35];
  const float* mlp_w1  = (const float*)d_in[36];
  const float* mlp_b1  = (const float*)d_in[37];
  const float* mlp_w2  = (const float*)d_in[38];
  const float* mlp_b2  = (const float*)d_in[39];
  const float* post_g  = (const float*)d_in[40];
  const float* post_b  = (const float*)d_in[41];

  // split-K ladder: pick the largest split whose partial buffer fits in ws
  const size_t base_elems = 1536 + 12ULL*1024*128 + 2ULL*12*1680*128; // 6,735,360
  int split = 2;
  {
    const int cand[3] = {8, 6, 4};
    for (int i = 0; i < 3; ++i) {
      size_t need = 4ULL*(base_elems + 1671168ULL*cand[i]);
      if (ws_size >= need) { split = cand[i]; break; }
    }
  }
  int kchunk = KPIX / split;
  int ntile  = kchunk / TK;
  int npart  = NN * split;

  float* ws = (float*)d_ws;
  float* c_embed = ws;
  float* qhb     = c_embed + 1536;
  float* khb     = qhb + 12ULL*1024*128;
  float* vhb     = khb + 12ULL*1680*128;
  float* partb   = vhb + 12ULL*1680*128;
  float* out     = (float*)d_out;

  hipLaunchKernelGGL(ce_kernel, dim3(BB*NN), dim3(128), 0, stream, cam_w, E_inv, c_embed);
  hipLaunchKernelGGL(kv_kernel, dim3(BB*NN*(KPIX/8)), dim3(256), 0, stream,
                     feature, I_inv, E_inv, image_plane, c_embed, img_w,
                     fp_bn_g, fp_bn_b, fp_bn_m, fp_bn_v, fp_w,
                     fl_bn_g, fl_bn_b, fl_bn_m, fl_bn_v, fl_w,
                     k_ln_g, k_ln_b, k_w, k_b,
                     v_ln_g, v_ln_b, v_w, v_b,
                     khb, vhb);
  hipLaunchKernelGGL(q_kernel, dim3(BB*NN*(QQ/8)), dim3(256), 0, stream,
                     x, bev_grid, bev_w, bev_b, c_embed,
                     q_ln_g, q_ln_b, q_w, q_b, qhb);
  hipLaunchKernelGGL(attn_kernel, dim3(BB*16*NN*split), dim3(256), 0, stream,
                     qhb, khb, vhb, partb, split, kchunk, ntile, npart);
  hipLaunchKernelGGL(epi_kernel, dim3(BB*QQ), dim3(128), 0, stream,
                     partb, x, proj_w, proj_b, pre_g, pre_b,
                     mlp_w1, mlp_b1, mlp_w2, mlp_b2, post_g, post_b, out, npart);
}

// Round 3
// 202.048 us; speedup vs baseline: 4.9727x; 1.8578x over previous
//
#include <hip/hip_runtime.h>
#include <math.h>

#define EPSF 1e-5f

// problem sizes
#define BB 2
#define NN 6
#define KPIX 1680      // 28*60
#define QQ 1024        // 32*32
#define SPLIT 4
#define KCHUNK (KPIX/SPLIT)   // 420
#define NPART (NN*SPLIT)      // 24
#define QSCALE 0.17677669529663687f  // 32^-0.5

typedef __attribute__((ext_vector_type(8))) short bf16x8;
typedef __attribute__((ext_vector_type(16))) float f32x16;

__device__ __forceinline__ float wred32(float v) {
#pragma unroll
  for (int off = 16; off > 0; off >>= 1) v += __shfl_xor(v, off, 32);
  return v;
}

__device__ __forceinline__ float blk_sum128(float v, float* s2, int t) {
#pragma unroll
  for (int off = 32; off > 0; off >>= 1) v += __shfl_down(v, off, 64);
  if ((t & 63) == 0) s2[t >> 6] = v;
  __syncthreads();
  float r = s2[0] + s2[1];
  __syncthreads();
  return r;
}

__device__ __forceinline__ unsigned short f2bf(float f) {
  union { float f; unsigned u; } v; v.f = f;
  unsigned r = v.u + 0x7FFFu + ((v.u >> 16) & 1u);   // RNE
  return (unsigned short)(r >> 16);
}

__device__ __forceinline__ unsigned pk_bf16(float lo, float hi) {
  unsigned r;
  asm volatile("v_cvt_pk_bf16_f32 %0, %1, %2" : "=v"(r) : "v"(lo), "v"(hi));
  return r;
}

// --- camera-center embedding
__global__ void ce_kernel(const float* __restrict__ cam_w, const float* __restrict__ E_inv,
                          float* __restrict__ c_embed) {
  int bn = blockIdx.x; int t = threadIdx.x;
  const float* E = E_inv + bn * 16;
  float s = cam_w[t*4+0]*E[3] + cam_w[t*4+1]*E[7] + cam_w[t*4+2]*E[11] + cam_w[t*4+3]*E[15];
  c_embed[bn*128 + t] = s;
}

// --- 8 pixels per block: img_embed + BN/ReLU/conv (fp,fl), K-LN+proj, V-LN+proj
// outputs: khb bf16 [bn*KPIX][128], vtb bf16 TRANSPOSED [bn][128][KPIX]
__global__ __launch_bounds__(256) void kv_kernel(
    const float* __restrict__ feature, const float* __restrict__ I_inv,
    const float* __restrict__ E_inv, const float* __restrict__ image_plane,
    const float* __restrict__ c_embed, const float* __restrict__ img_w,
    const float* __restrict__ fp_bn_g, const float* __restrict__ fp_bn_b,
    const float* __restrict__ fp_bn_m, const float* __restrict__ fp_bn_v,
    const float* __restrict__ fp_w,
    const float* __restrict__ fl_bn_g, const float* __restrict__ fl_bn_b,
    const float* __restrict__ fl_bn_m, const float* __restrict__ fl_bn_v,
    const float* __restrict__ fl_w,
    const float* __restrict__ k_ln_g, const float* __restrict__ k_ln_b,
    const float* __restrict__ k_w, const float* __restrict__ k_b,
    const float* __restrict__ v_ln_g, const float* __restrict__ v_ln_b,
    const float* __restrict__ v_w, const float* __restrict__ v_b,
    unsigned short* __restrict__ khb, unsigned short* __restrict__ vtb)
{
  int blk = blockIdx.x;
  int bn = blk / (KPIX/8), kc = blk % (KPIX/8);
  int k0 = kc * 8;
  int t = threadIdx.x;
  __shared__ float s_fp[1024], s_fl[1024], s_ime[1024], s_k[1024], s_v[1024];

  {
    int l = t & 31, p = t >> 5;
    int k = k0 + p;
    const float* Ii = I_inv + bn*9;
    const float* Ei = E_inv + bn*16;
    float px = image_plane[k], py = image_plane[KPIX + k], pz = image_plane[2*KPIX + k];
    float c0 = Ii[0]*px + Ii[1]*py + Ii[2]*pz;
    float c1 = Ii[3]*px + Ii[4]*py + Ii[5]*pz;
    float c2 = Ii[6]*px + Ii[7]*py + Ii[8]*pz;
    float d0 = Ei[0]*c0 + Ei[1]*c1 + Ei[2]*c2  + Ei[3];
    float d1 = Ei[4]*c0 + Ei[5]*c1 + Ei[6]*c2  + Ei[7];
    float d2 = Ei[8]*c0 + Ei[9]*c1 + Ei[10]*c2 + Ei[11];
    float d3 = Ei[12]*c0 + Ei[13]*c1 + Ei[14]*c2 + Ei[15];
    float imv[4]; float ss = 0.f;
#pragma unroll
    for (int j = 0; j < 4; ++j) {
      int o = l + 32*j;
      float de = img_w[o*4+0]*d0 + img_w[o*4+1]*d1 + img_w[o*4+2]*d2 + img_w[o*4+3]*d3;
      float ime = de - c_embed[bn*128 + o];
      imv[j] = ime; ss += ime*ime;
    }
    ss = wred32(ss);
    float rinv = 1.f/(sqrtf(ss) + 1e-7f);
#pragma unroll
    for (int j = 0; j < 4; ++j) {
      int o = l + 32*j;
      s_ime[o*8 + p] = imv[j]*rinv;
      float f = feature[((size_t)(bn*128 + o))*KPIX + k];
      float thp = (f - fp_bn_m[o]) * (fp_bn_g[o]*rsqrtf(fp_bn_v[o]+EPSF)) + fp_bn_b[o];
      float thl = (f - fl_bn_m[o]) * (fl_bn_g[o]*rsqrtf(fl_bn_v[o]+EPSF)) + fl_bn_b[o];
      s_fp[o*8 + p] = fmaxf(thp, 0.f);
      s_fl[o*8 + p] = fmaxf(thl, 0.f);
    }
  }
  __syncthreads();

  int oo = t & 127, h = t >> 7;
  {
    float ka0=0,ka1=0,ka2=0,ka3=0, va0=0,va1=0,va2=0,va3=0;
    const float* wp = fp_w + (size_t)oo*128;
    const float* wl = fl_w + (size_t)oo*128;
#pragma unroll 8
    for (int c = 0; c < 128; ++c) {
      float wfp = wp[c], wfl = wl[c];
      float4 afp = *(const float4*)&s_fp[c*8 + h*4];
      float4 afl = *(const float4*)&s_fl[c*8 + h*4];
      ka0 += wfp*afp.x; ka1 += wfp*afp.y; ka2 += wfp*afp.z; ka3 += wfp*afp.w;
      va0 += wfl*afl.x; va1 += wfl*afl.y; va2 += wfl*afl.z; va3 += wfl*afl.w;
    }
    float4 im4 = *(const float4*)&s_ime[oo*8 + h*4];
    ka0 += im4.x; ka1 += im4.y; ka2 += im4.z; ka3 += im4.w;
    *(float4*)&s_k[oo*8 + h*4] = make_float4(ka0,ka1,ka2,ka3);
    *(float4*)&s_v[oo*8 + h*4] = make_float4(va0,va1,va2,va3);
  }
  __syncthreads();

  {
    int l = t & 31, p = t >> 5;
    float kj[4], vj[4];
    float s1k=0,s2k=0,s1v=0,s2v=0;
#pragma unroll
    for (int j = 0; j < 4; ++j) {
      int o = l + 32*j;
      float a = s_k[o*8 + p]; kj[j] = a; s1k += a; s2k += a*a;
      float bq = s_v[o*8 + p]; vj[j] = bq; s1v += bq; s2v += bq*bq;
    }
    s1k = wred32(s1k); s2k = wred32(s2k); s1v = wred32(s1v); s2v = wred32(s2v);
    float muk = s1k*(1.f/128.f), vark = s2k*(1.f/128.f) - muk*muk;
    float muv = s1v*(1.f/128.f), varv = s2v*(1.f/128.f) - muv*muv;
    float rsk = rsqrtf(vark + EPSF), rsv = rsqrtf(varv + EPSF);
#pragma unroll
    for (int j = 0; j < 4; ++j) {
      int o = l + 32*j;
      s_k[o*8 + p] = (kj[j]-muk)*rsk*k_ln_g[o] + k_ln_b[o];
      s_v[o*8 + p] = (vj[j]-muv)*rsv*v_ln_g[o] + v_ln_b[o];
    }
  }
  __syncthreads();

  {
    float kb = k_b[oo], vb = v_b[oo];
    float k0a=kb,k1a=kb,k2a=kb,k3a=kb, v0a=vb,v1a=vb,v2a=vb,v3a=vb;
#pragma unroll 8
    for (int o2 = 0; o2 < 128; ++o2) {
      float wk = k_w[(size_t)o2*128 + oo];
      float wv = v_w[(size_t)o2*128 + oo];
      float4 ak = *(const float4*)&s_k[o2*8 + h*4];
      float4 av = *(const float4*)&s_v[o2*8 + h*4];
      k0a += wk*ak.x; k1a += wk*ak.y; k2a += wk*ak.z; k3a += wk*ak.w;
      v0a += wv*av.x; v1a += wv*av.y; v2a += wv*av.z; v3a += wv*av.w;
    }
    float ko[4] = {k0a,k1a,k2a,k3a}, vo[4] = {v0a,v1a,v2a,v3a};
#pragma unroll
    for (int pp = 0; pp < 4; ++pp)
      khb[((size_t)bn*KPIX + (k0 + h*4 + pp))*128 + oo] = f2bf(ko[pp]);
    ushort4 vv = make_ushort4(f2bf(vo[0]), f2bf(vo[1]), f2bf(vo[2]), f2bf(vo[3]));
    *(ushort4*)(vtb + ((size_t)bn*128 + oo)*KPIX + k0 + h*4) = vv;
  }
}

// --- 8 queries per block: bev embed + x, LN, q-proj; out bf16 with 1/sqrt(32) folded
__global__ __launch_bounds__(256) void q_kernel(
    const float* __restrict__ x, const float* __restrict__ bev_grid,
    const float* __restrict__ bev_w, const float* __restrict__ bev_b,
    const float* __restrict__ c_embed,
    const float* __restrict__ q_ln_g, const float* __restrict__ q_ln_b,
    const float* __restrict__ q_w, const float* __restrict__ q_b,
    unsigned short* __restrict__ qhb)
{
  int blk = blockIdx.x;
  int bn = blk >> 7, qc = blk & 127;
  int q0 = qc * 8;
  int b = bn / NN;
  int t = threadIdx.x;
  __shared__ float s_q[1024];

  {
    int l = t & 31, p = t >> 5;
    int qi = q0 + p;
    float gx = bev_grid[qi], gy = bev_grid[QQ + qi];
    float vj[4]; float ss = 0.f;
#pragma unroll
    for (int j = 0; j < 4; ++j) {
      int o = l + 32*j;
      float we = bev_w[o*2+0]*gx + bev_w[o*2+1]*gy + bev_b[o];
      float be = we - c_embed[bn*128 + o];
      vj[j] = be; ss += be*be;
    }
    ss = wred32(ss);
    float rinv = 1.f/(sqrtf(ss) + 1e-7f);
    float s1 = 0.f, s2 = 0.f;
#pragma unroll
    for (int j = 0; j < 4; ++j) {
      int o = l + 32*j;
      float qv = vj[j]*rinv + x[((size_t)(b*128 + o))*QQ + qi];
      vj[j] = qv; s1 += qv; s2 += qv*qv;
    }
    s1 = wred32(s1); s2 = wred32(s2);
    float mu = s1*(1.f/128.f), var = s2*(1.f/128.f) - mu*mu;
    float rs = rsqrtf(var + EPSF);
#pragma unroll
    for (int j = 0; j < 4; ++j) {
      int o = l + 32*j;
      s_q[o*8 + p] = (vj[j]-mu)*rs*q_ln_g[o] + q_ln_b[o];
    }
  }
  __syncthreads();

  {
    int oo = t & 127, h = t >> 7;
    float qb = q_b[oo];
    float a0=qb,a1=qb,a2=qb,a3=qb;
#pragma unroll 8
    for (int o2 = 0; o2 < 128; ++o2) {
      float w = q_w[(size_t)o2*128 + oo];
      float4 a = *(const float4*)&s_q[o2*8 + h*4];
      a0 += w*a.x; a1 += w*a.y; a2 += w*a.z; a3 += w*a.w;
    }
    float qo[4] = {a0,a1,a2,a3};
#pragma unroll
    for (int pp = 0; pp < 4; ++pp)
      qhb[((size_t)bn*QQ + (q0 + h*4 + pp))*128 + oo] = f2bf(qo[pp] * QSCALE);
  }
}

// --- MFMA flash attention partials. block = (b, qt32, n, sp); wave = head.
// Swapped QK^T: S^T = mfma(K_frag, Q_frag) -> lane holds 16 scores for q = lane&31.
// Fixed softmax shift m==0 (exact after epi renorm). P packed to bf16 via cvt_pk +
// shfl_xor(32) half-swaps, feeds PV A-operand directly. V read from transposed vtb.
__global__ __launch_bounds__(256) void attn_kernel(
    const unsigned short* __restrict__ qhb, const unsigned short* __restrict__ khb,
    const unsigned short* __restrict__ vtb,
    float* __restrict__ lsum, float* __restrict__ pacc)
{
  int blk = blockIdx.x;
  int sp = blk % SPLIT; blk /= SPLIT;
  int n  = blk % NN;    blk /= NN;
  int qt = blk % 32;    blk /= 32;
  int b  = blk;
  int t = threadIdx.x;
  int wave = t >> 6;
  int l = t & 63;
  int lo = l & 31;
  int hi = l >> 5;
  int dho = wave * 32;
  int bn = b*NN + n;

  const unsigned short* qrow = qhb + ((size_t)bn*QQ + qt*32 + lo)*128 + dho + hi*8;
  bf16x8 qf0 = *(const bf16x8*)(qrow);
  bf16x8 qf1 = *(const bf16x8*)(qrow + 16);

  f32x16 acc = {};
  float lrun = 0.f;

  int k0 = sp * KCHUNK;
  int kend = k0 + KCHUNK;

  const unsigned short* kbase = khb + (size_t)bn*KPIX*128 + dho + hi*8;
  const unsigned short* vrow  = vtb + ((size_t)bn*128 + dho + lo)*KPIX;

  for (int K0 = k0; K0 < kend; K0 += 32) {
    const unsigned short* krow = kbase + (size_t)(K0 + lo)*128;
    bf16x8 kf0 = *(const bf16x8*)(krow);
    bf16x8 kf1 = *(const bf16x8*)(krow + 16);
    bf16x8 vf0 = *(const bf16x8*)(vrow + K0 + hi*8);
    bf16x8 vf1 = *(const bf16x8*)(vrow + K0 + 16 + hi*8);

    f32x16 s = {};
    s = __builtin_amdgcn_mfma_f32_32x32x16_bf16(kf0, qf0, s, 0, 0, 0);
    s = __builtin_amdgcn_mfma_f32_32x32x16_bf16(kf1, qf1, s, 0, 0, 0);

    float p[16];
    if (K0 + 32 <= kend) {
#pragma unroll
      for (int r = 0; r < 16; ++r) { float e = __expf(s[r]); p[r] = e; lrun += e; }
    } else {
#pragma unroll
      for (int r = 0; r < 16; ++r) {
        int key = K0 + (r&3) + 8*(r>>2) + 4*hi;
        float e = (key < kend) ? __expf(s[r]) : 0.f;
        p[r] = e; lrun += e;
      }
    }

#pragma unroll
    for (int ks = 0; ks < 2; ++ks) {
      int rb = ks*8;
      unsigned a0 = pk_bf16(p[rb+0], p[rb+1]);   // hi=0: keys(+0,+1) | hi=1: keys(+4,+5)
      unsigned c0 = pk_bf16(p[rb+2], p[rb+3]);   // hi=0: keys(+2,+3) | hi=1: keys(+6,+7)
      unsigned b0 = pk_bf16(p[rb+4], p[rb+5]);   // hi=0: keys(+8,+9) | hi=1: keys(+12,+13)
      unsigned d0 = pk_bf16(p[rb+6], p[rb+7]);   // hi=0: keys(+10,+11)| hi=1: keys(+14,+15)
      unsigned sa = (unsigned)__shfl_xor((int)a0, 32);
      unsigned sc = (unsigned)__shfl_xor((int)c0, 32);
      unsigned sb = (unsigned)__shfl_xor((int)b0, 32);
      unsigned sd = (unsigned)__shfl_xor((int)d0, 32);
      union { unsigned u[4]; bf16x8 v; } pa;
      pa.u[0] = hi ? sb : a0;   // keys hi*8 + (0,1)
      pa.u[1] = hi ? sd : c0;   // keys hi*8 + (2,3)
      pa.u[2] = hi ? b0 : sa;   // keys hi*8 + (4,5)
      pa.u[3] = hi ? d0 : sc;   // keys hi*8 + (6,7)
      acc = __builtin_amdgcn_mfma_f32_32x32x16_bf16(pa.v, ks ? vf1 : vf0, acc, 0, 0, 0);
    }
  }

  float ltot = lrun + __shfl_xor(lrun, 32);
  int j = n*SPLIT + sp;
  size_t hb = ((size_t)(b*4 + wave)*NPART + j)*QQ;
  if (hi == 0) lsum[hb + qt*32 + lo] = ltot;
#pragma unroll
  for (int r = 0; r < 16; ++r) {
    int crow = (r&3) + 8*(r>>2) + 4*hi;
    pacc[(hb + qt*32 + crow)*32 + lo] = acc[r];
  }
}

// --- combine partials + proj + skip + preLN + MLP(gelu) + postLN + transposed store
__global__ __launch_bounds__(128) void epi_kernel(
    const float* __restrict__ lsum, const float* __restrict__ pacc,
    const float* __restrict__ x,
    const float* __restrict__ proj_w, const float* __restrict__ proj_b,
    const float* __restrict__ pre_g, const float* __restrict__ pre_b,
    const float* __restrict__ mlp_w1, const float* __restrict__ mlp_b1,
    const float* __restrict__ mlp_w2, const float* __restrict__ mlp_b2,
    const float* __restrict__ post_g, const float* __restrict__ post_b,
    float* __restrict__ out)
{
  int blk = blockIdx.x;
  int b = blk / QQ, q = blk % QQ;
  int t = threadIdx.x;
  int d = t & 31, m = t >> 5;
  __shared__ float s_a[128], s_z[128], s_h[256], s_red[2];

  size_t hb = (size_t)(b*4 + m)*NPART*QQ;
  float lt = 0.f, av = 0.f;
#pragma unroll 4
  for (int j = 0; j < NPART; ++j) {
    lt += lsum[hb + (size_t)j*QQ + q];
    av += pacc[(hb + (size_t)j*QQ + q)*32 + d];
  }
  s_a[t] = av / lt;
  __syncthreads();

  float z = proj_b[t] + x[((size_t)b*128 + t)*QQ + q];
#pragma unroll 8
  for (int i = 0; i < 128; ++i) z += s_a[i]*proj_w[i*128 + t];
  float mu = blk_sum128(z, s_red, t)*(1.f/128.f);
  float dv = z - mu;
  float var = blk_sum128(dv*dv, s_red, t)*(1.f/128.f);
  float zn = dv*rsqrtf(var + EPSF)*pre_g[t] + pre_b[t];
  s_z[t] = zn;
  __syncthreads();
  float h0 = mlp_b1[t], h1 = mlp_b1[t+128];
#pragma unroll 8
  for (int o = 0; o < 128; ++o) {
    float zo = s_z[o];
    h0 += zo*mlp_w1[o*256 + t];
    h1 += zo*mlp_w1[o*256 + t + 128];
  }
  s_h[t]     = 0.5f*h0*(1.f + erff(h0*0.7071067811865476f));
  s_h[t+128] = 0.5f*h1*(1.f + erff(h1*0.7071067811865476f));
  __syncthreads();
  float mo = mlp_b2[t];
#pragma unroll 8
  for (int hh = 0; hh < 256; ++hh) mo += s_h[hh]*mlp_w2[hh*128 + t];
  float z2 = zn + mo;
  mu = blk_sum128(z2, s_red, t)*(1.f/128.f);
  dv = z2 - mu;
  var = blk_sum128(dv*dv, s_red, t)*(1.f/128.f);
  float o2 = dv*rsqrtf(var + EPSF)*post_g[t] + post_b[t];
  out[((size_t)b*128 + t)*QQ + q] = o2;
}

extern "C" void kernel_launch(void* const* d_in, const int* in_sizes, int n_in,
                              void* d_out, int out_size, void* d_ws, size_t ws_size,
                              hipStream_t stream) {
  const float* x           = (const float*)d_in[0];
  const float* feature     = (const float*)d_in[1];
  const float* I_inv       = (const float*)d_in[2];
  const float* E_inv       = (const float*)d_in[3];
  const float* bev_grid    = (const float*)d_in[4];
  const float* image_plane = (const float*)d_in[5];
  const float* fl_bn_g = (const float*)d_in[6];
  const float* fl_bn_b = (const float*)d_in[7];
  const float* fl_bn_m = (const float*)d_in[8];
  const float* fl_bn_v = (const float*)d_in[9];
  const float* fl_w    = (const float*)d_in[10];
  const float* fp_bn_g = (const float*)d_in[11];
  const float* fp_bn_b = (const float*)d_in[12];
  const float* fp_bn_m = (const float*)d_in[13];
  const float* fp_bn_v = (const float*)d_in[14];
  const float* fp_w    = (const float*)d_in[15];
  const float* bev_w   = (const float*)d_in[16];
  const float* bev_b   = (const float*)d_in[17];
  const float* img_w   = (const float*)d_in[18];
  const float* cam_w   = (const float*)d_in[19];
  const float* q_ln_g  = (const float*)d_in[20];
  const float* q_ln_b  = (const float*)d_in[21];
  const float* q_w     = (const float*)d_in[22];
  const float* q_b     = (const float*)d_in[23];
  const float* k_ln_g  = (const float*)d_in[24];
  const float* k_ln_b  = (const float*)d_in[25];
  const float* k_w     = (const float*)d_in[26];
  const float* k_b     = (const float*)d_in[27];
  const float* v_ln_g  = (const float*)d_in[28];
  const float* v_ln_b  = (const float*)d_in[29];
  const float* v_w     = (const float*)d_in[30];
  const float* v_b     = (const float*)d_in[31];
  const float* proj_w  = (const float*)d_in[32];
  const float* proj_b  = (const float*)d_in[33];
  const float* pre_g   = (const float*)d_in[34];
  const float* pre_b   = (const float*)d_in[35];
  const float* mlp_w1  = (const float*)d_in[36];
  const float* mlp_b1  = (const float*)d_in[37];
  const float* mlp_w2  = (const float*)d_in[38];
  const float* mlp_b2  = (const float*)d_in[39];
  const float* post_g  = (const float*)d_in[40];
  const float* post_b  = (const float*)d_in[41];

  // workspace layout (f32 first, then 16B-aligned bf16 buffers; vtb LAST so
  // masked tail-tile over-reads land in finite poison, never f32-as-bf16 NaNs)
  float* ws = (float*)d_ws;
  float* c_embed = ws;                                        // 1536
  float* lsum = ws + 1536;                                    // 2*4*24*1024      = 196608
  float* pacc = lsum + (size_t)BB*4*NPART*QQ;                 // *32              = 6291456
  unsigned short* qhb = (unsigned short*)(pacc + (size_t)BB*4*NPART*QQ*32);
  unsigned short* khb = qhb + (size_t)BB*NN*QQ*128;           // 12*1024*128
  unsigned short* vtb = khb + (size_t)BB*NN*KPIX*128;         // 12*1680*128
  float* out = (float*)d_out;

  hipLaunchKernelGGL(ce_kernel, dim3(BB*NN), dim3(128), 0, stream, cam_w, E_inv, c_embed);
  hipLaunchKernelGGL(kv_kernel, dim3(BB*NN*(KPIX/8)), dim3(256), 0, stream,
                     feature, I_inv, E_inv, image_plane, c_embed, img_w,
                     fp_bn_g, fp_bn_b, fp_bn_m, fp_bn_v, fp_w,
                     fl_bn_g, fl_bn_b, fl_bn_m, fl_bn_v, fl_w,
                     k_ln_g, k_ln_b, k_w, k_b,
                     v_ln_g, v_ln_b, v_w, v_b,
                     khb, vtb);
  hipLaunchKernelGGL(q_kernel, dim3(BB*NN*(QQ/8)), dim3(256), 0, stream,
                     x, bev_grid, bev_w, bev_b, c_embed,
                     q_ln_g, q_ln_b, q_w, q_b, qhb);
  hipLaunchKernelGGL(attn_kernel, dim3(BB*32*NN*SPLIT), dim3(256), 0, stream,
                     qhb, khb, vtb, lsum, pacc);
  hipLaunchKernelGGL(epi_kernel, dim3(BB*QQ), dim3(128), 0, stream,
                     lsum, pacc, x, proj_w, proj_b, pre_g, pre_b,
                     mlp_w1, mlp_b1, mlp_w2, mlp_b2, post_g, post_b, out);
}

// Round 4
// 113.527 us; speedup vs baseline: 8.8501x; 1.7797x over previous
//
#include <hip/hip_runtime.h>
#include <math.h>

#define EPSF 1e-5f

// problem sizes
#define BB 2
#define NN 6
#define KPIX 1680      // 28*60
#define QQ 1024        // 32*32
#define SPLIT 4
#define KCHUNK (KPIX/SPLIT)   // 420
#define NPART (NN*SPLIT)      // 24
#define QSCALE 0.17677669529663687f  // 32^-0.5
#define NTILE_KV 53    // ceil(1680/32); last tile has 16 valid pixels

typedef __attribute__((ext_vector_type(8))) short bf16x8;
typedef __attribute__((ext_vector_type(16))) float f32x16;

__device__ __forceinline__ float blk_sum128(float v, float* s2, int t) {
#pragma unroll
  for (int off = 32; off > 0; off >>= 1) v += __shfl_down(v, off, 64);
  if ((t & 63) == 0) s2[t >> 6] = v;
  __syncthreads();
  float r = s2[0] + s2[1];
  __syncthreads();
  return r;
}

__device__ __forceinline__ unsigned short f2bf(float f) {
  union { float f; unsigned u; } v; v.f = f;
  unsigned r = v.u + 0x7FFFu + ((v.u >> 16) & 1u);   // RNE
  return (unsigned short)(r >> 16);
}

__device__ __forceinline__ unsigned pk_bf16(float lo, float hi) {
  unsigned r;
  asm volatile("v_cvt_pk_bf16_f32 %0, %1, %2" : "=v"(r) : "v"(lo), "v"(hi));
  return r;
}

// --- weight prepack to bf16 fragment-friendly layouts:
// mat0: fp_w [o][c] row-major; mat1: fl_w [o][c];
// mat2: k_w^T [o2][c]; mat3: v_w^T [o2][c]; mat4: q_w^T [o2][c] * QSCALE
__global__ void prepack_kernel(const float* __restrict__ fp_w, const float* __restrict__ fl_w,
                               const float* __restrict__ k_w, const float* __restrict__ v_w,
                               const float* __restrict__ q_w, unsigned short* __restrict__ wp) {
  int mat = blockIdx.x >> 7;
  int o = blockIdx.x & 127;
  int c = threadIdx.x;
  float v;
  if (mat == 0)      v = fp_w[o*128 + c];
  else if (mat == 1) v = fl_w[o*128 + c];
  else if (mat == 2) v = k_w[c*128 + o];
  else if (mat == 3) v = v_w[c*128 + o];
  else               v = q_w[c*128 + o] * QSCALE;
  wp[(size_t)mat*16384 + o*128 + c] = f2bf(v);
}

// --- camera-center embedding
__global__ void ce_kernel(const float* __restrict__ cam_w, const float* __restrict__ E_inv,
                          float* __restrict__ c_embed) {
  int bn = blockIdx.x; int t = threadIdx.x;
  const float* E = E_inv + bn * 16;
  float s = cam_w[t*4+0]*E[3] + cam_w[t*4+1]*E[7] + cam_w[t*4+2]*E[11] + cam_w[t*4+3]*E[15];
  c_embed[bn*128 + t] = s;
}

// --- MFMA kv: block = (bn, 32-pixel tile). 4 waves own 32 output rows each.
// GEMM1 (conv fp/fl) -> +normalized img_embed (K only) -> per-pixel LN -> GEMM2 (k/v proj)
// outputs: khb bf16 [bn*KPIX][128], vtb bf16 TRANSPOSED [bn][128][KPIX]
__global__ __launch_bounds__(256) void kv_kernel(
    const float* __restrict__ feature, const float* __restrict__ I_inv,
    const float* __restrict__ E_inv, const float* __restrict__ image_plane,
    const float* __restrict__ c_embed, const float* __restrict__ img_w,
    const float* __restrict__ fp_bn_g, const float* __restrict__ fp_bn_b,
    const float* __restrict__ fp_bn_m, const float* __restrict__ fp_bn_v,
    const float* __restrict__ fl_bn_g, const float* __restrict__ fl_bn_b,
    const float* __restrict__ fl_bn_m, const float* __restrict__ fl_bn_v,
    const float* __restrict__ k_ln_g, const float* __restrict__ k_ln_b,
    const float* __restrict__ k_b,
    const float* __restrict__ v_ln_g, const float* __restrict__ v_ln_b,
    const float* __restrict__ v_b,
    const unsigned short* __restrict__ wp,
    unsigned short* __restrict__ khb, unsigned short* __restrict__ vtb)
{
  int blk = blockIdx.x;
  int bn = blk / NTILE_KV, tp = blk % NTILE_KV;
  int p0 = tp * 32;
  int t = threadIdx.x;
  int wv = t >> 6, l = t & 63, lo = l & 31, hi = l >> 5;

  __shared__ unsigned short sA[2][32*128];   // [path][p][c], XOR-swizzled; 16 KB
  __shared__ float sD[4][32];                // per-pixel ray 4-vector
  __shared__ float sRed[5][4][32];           // cross-wave reduce scratch

  // ---- phase A0: per-pixel ray d-vector (threads 0..31) ----
  if (t < 32) {
    int pix = min(p0 + t, KPIX-1);
    const float* Ii = I_inv + bn*9;
    const float* Ei = E_inv + bn*16;
    float px = image_plane[pix], py = image_plane[KPIX + pix], pz = image_plane[2*KPIX + pix];
    float c0 = Ii[0]*px + Ii[1]*py + Ii[2]*pz;
    float c1 = Ii[3]*px + Ii[4]*py + Ii[5]*pz;
    float c2 = Ii[6]*px + Ii[7]*py + Ii[8]*pz;
    sD[0][t] = Ei[0]*c0 + Ei[1]*c1 + Ei[2]*c2  + Ei[3];
    sD[1][t] = Ei[4]*c0 + Ei[5]*c1 + Ei[6]*c2  + Ei[7];
    sD[2][t] = Ei[8]*c0 + Ei[9]*c1 + Ei[10]*c2 + Ei[11];
    sD[3][t] = Ei[12]*c0 + Ei[13]*c1 + Ei[14]*c2 + Ei[15];
  }

  // ---- phase A1: feature -> BN+ReLU -> bf16 LDS tiles [p][c] ----
  {
    int c = t >> 1, ph = t & 1;
    float gp = fp_bn_g[c]*rsqrtf(fp_bn_v[c]+EPSF); float bp = fp_bn_b[c] - fp_bn_m[c]*gp;
    float gl = fl_bn_g[c]*rsqrtf(fl_bn_v[c]+EPSF); float bl = fl_bn_b[c] - fl_bn_m[c]*gl;
    const float* frow = feature + ((size_t)bn*128 + c)*KPIX;
#pragma unroll
    for (int i = 0; i < 4; ++i) {
      int plb = ph*16 + 4*i;
      int pix = p0 + plb;
      float4 f;
      if (pix + 3 < KPIX) f = *(const float4*)(frow + pix);
      else {
        f.x = frow[min(pix+0, KPIX-1)]; f.y = frow[min(pix+1, KPIX-1)];
        f.z = frow[min(pix+2, KPIX-1)]; f.w = frow[min(pix+3, KPIX-1)];
      }
      float fv[4] = {f.x, f.y, f.z, f.w};
#pragma unroll
      for (int j = 0; j < 4; ++j) {
        int pl = plb + j;
        int cc = c ^ ((pl & 7) << 3);
        sA[0][pl*128 + cc] = f2bf(fmaxf(fv[j]*gp + bp, 0.f));
        sA[1][pl*128 + cc] = f2bf(fmaxf(fv[j]*gl + bl, 0.f));
      }
    }
  }
  __syncthreads();

  // ---- GEMM1: K_base = fp_w @ A_fp ; V_base = fl_w @ A_fl ----
  f32x16 acck = {}, accv = {};
  {
    const unsigned short* wfp = wp + (size_t)0*16384 + (32*wv + lo)*128 + hi*8;
    const unsigned short* wfl = wp + (size_t)1*16384 + (32*wv + lo)*128 + hi*8;
    int swz = (lo & 7) << 3;
#pragma unroll
    for (int s = 0; s < 8; ++s) {
      int cbase = s*16 + hi*8;
      bf16x8 a0 = *(const bf16x8*)(wfp + s*16);
      bf16x8 a1 = *(const bf16x8*)(wfl + s*16);
      bf16x8 b0 = *(const bf16x8*)&sA[0][lo*128 + (cbase ^ swz)];
      bf16x8 b1 = *(const bf16x8*)&sA[1][lo*128 + (cbase ^ swz)];
      acck = __builtin_amdgcn_mfma_f32_32x32x16_bf16(a0, b0, acck, 0, 0, 0);
      accv = __builtin_amdgcn_mfma_f32_32x32x16_bf16(a1, b1, accv, 0, 0, 0);
    }
  }

  // C layout: col(pixel) = lo, row = (r&3)+8*(r>>2)+4*hi (+32*wv absolute)
  float d0 = sD[0][lo], d1 = sD[1][lo], d2 = sD[2][lo], d3 = sD[3][lo];

  // ---- img_embed + stats pass 1 (ime ss, V s1/s2) ----
  float ime[16];
  float ss = 0.f, vs1 = 0.f, vs2 = 0.f;
#pragma unroll
  for (int r = 0; r < 16; ++r) {
    int o = 32*wv + (r&3) + 8*(r>>2) + 4*hi;
    float4 iw = *(const float4*)(img_w + o*4);
    float de = iw.x*d0 + iw.y*d1 + iw.z*d2 + iw.w*d3 - c_embed[bn*128 + o];
    ime[r] = de; ss += de*de;
    float vv = accv[r];
    vs1 += vv; vs2 += vv*vv;
  }
  ss  += __shfl_xor(ss, 32);
  vs1 += __shfl_xor(vs1, 32);
  vs2 += __shfl_xor(vs2, 32);
  if (hi == 0) { sRed[0][wv][lo] = ss; sRed[1][wv][lo] = vs1; sRed[2][wv][lo] = vs2; }
  __syncthreads();
  float sst  = sRed[0][0][lo]+sRed[0][1][lo]+sRed[0][2][lo]+sRed[0][3][lo];
  float vs1t = sRed[1][0][lo]+sRed[1][1][lo]+sRed[1][2][lo]+sRed[1][3][lo];
  float vs2t = sRed[2][0][lo]+sRed[2][1][lo]+sRed[2][2][lo]+sRed[2][3][lo];
  float rinv = 1.f/(sqrtf(sst) + 1e-7f);
  float vmu = vs1t*(1.f/128.f);
  float vrs = rsqrtf(vs2t*(1.f/128.f) - vmu*vmu + EPSF);

  // ---- apply ime, K stats pass 2 ----
  float kval[16];
  float ks1 = 0.f, ks2 = 0.f;
#pragma unroll
  for (int r = 0; r < 16; ++r) {
    float kv2 = acck[r] + ime[r]*rinv;
    kval[r] = kv2; ks1 += kv2; ks2 += kv2*kv2;
  }
  ks1 += __shfl_xor(ks1, 32);
  ks2 += __shfl_xor(ks2, 32);
  if (hi == 0) { sRed[3][wv][lo] = ks1; sRed[4][wv][lo] = ks2; }
  __syncthreads();
  float ks1t = sRed[3][0][lo]+sRed[3][1][lo]+sRed[3][2][lo]+sRed[3][3][lo];
  float ks2t = sRed[4][0][lo]+sRed[4][1][lo]+sRed[4][2][lo]+sRed[4][3][lo];
  float kmu = ks1t*(1.f/128.f);
  float krs = rsqrtf(ks2t*(1.f/128.f) - kmu*kmu + EPSF);

  // ---- LN apply, write kn/vn bf16 tiles (reuse sA; all GEMM1 reads done) ----
  {
    int swz = (lo & 7) << 3;
#pragma unroll
    for (int g = 0; g < 4; ++g) {
      int ob = 32*wv + 8*g + 4*hi;
      float4 kg = *(const float4*)(k_ln_g + ob);
      float4 kb2 = *(const float4*)(k_ln_b + ob);
      float4 vg = *(const float4*)(v_ln_g + ob);
      float4 vb2 = *(const float4*)(v_ln_b + ob);
      float kn0 = (kval[4*g+0]-kmu)*krs*kg.x + kb2.x;
      float kn1 = (kval[4*g+1]-kmu)*krs*kg.y + kb2.y;
      float kn2 = (kval[4*g+2]-kmu)*krs*kg.z + kb2.z;
      float kn3 = (kval[4*g+3]-kmu)*krs*kg.w + kb2.w;
      float vn0 = (accv[4*g+0]-vmu)*vrs*vg.x + vb2.x;
      float vn1 = (accv[4*g+1]-vmu)*vrs*vg.y + vb2.y;
      float vn2 = (accv[4*g+2]-vmu)*vrs*vg.z + vb2.z;
      float vn3 = (accv[4*g+3]-vmu)*vrs*vg.w + vb2.w;
      int idx = lo*128 + (ob ^ swz);
      *(ushort4*)&sA[0][idx] = make_ushort4(f2bf(kn0), f2bf(kn1), f2bf(kn2), f2bf(kn3));
      *(ushort4*)&sA[1][idx] = make_ushort4(f2bf(vn0), f2bf(vn1), f2bf(vn2), f2bf(vn3));
    }
  }
  __syncthreads();

  // ---- GEMM2: kh = k_w^T @ kn + k_b ; vh = v_w^T @ vn + v_b ----
  f32x16 a2k = {}, a2v = {};
  {
    const unsigned short* wk = wp + (size_t)2*16384 + (32*wv + lo)*128 + hi*8;
    const unsigned short* wv2 = wp + (size_t)3*16384 + (32*wv + lo)*128 + hi*8;
    int swz = (lo & 7) << 3;
#pragma unroll
    for (int s = 0; s < 8; ++s) {
      int cbase = s*16 + hi*8;
      bf16x8 a0 = *(const bf16x8*)(wk + s*16);
      bf16x8 a1 = *(const bf16x8*)(wv2 + s*16);
      bf16x8 b0 = *(const bf16x8*)&sA[0][lo*128 + (cbase ^ swz)];
      bf16x8 b1 = *(const bf16x8*)&sA[1][lo*128 + (cbase ^ swz)];
      a2k = __builtin_amdgcn_mfma_f32_32x32x16_bf16(a0, b0, a2k, 0, 0, 0);
      a2v = __builtin_amdgcn_mfma_f32_32x32x16_bf16(a1, b1, a2v, 0, 0, 0);
    }
  }

  // ---- stores (masked on tail tile) ----
  int pix = p0 + lo;
  if (pix < KPIX) {
    unsigned short* krow = khb + ((size_t)bn*KPIX + pix)*128;
#pragma unroll
    for (int g = 0; g < 4; ++g) {
      int ob = 32*wv + 8*g + 4*hi;
      float4 kb4 = *(const float4*)(k_b + ob);
      *(ushort4*)(krow + ob) = make_ushort4(
        f2bf(a2k[4*g+0] + kb4.x), f2bf(a2k[4*g+1] + kb4.y),
        f2bf(a2k[4*g+2] + kb4.z), f2bf(a2k[4*g+3] + kb4.w));
      float4 vb4 = *(const float4*)(v_b + ob);
      vtb[((size_t)bn*128 + ob+0)*KPIX + pix] = f2bf(a2v[4*g+0] + vb4.x);
      vtb[((size_t)bn*128 + ob+1)*KPIX + pix] = f2bf(a2v[4*g+1] + vb4.y);
      vtb[((size_t)bn*128 + ob+2)*KPIX + pix] = f2bf(a2v[4*g+2] + vb4.z);
      vtb[((size_t)bn*128 + ob+3)*KPIX + pix] = f2bf(a2v[4*g+3] + vb4.w);
    }
  }
}

// --- MFMA q: block = (bn, 32-query tile). bev embed + x, LN, q-proj (scale folded).
__global__ __launch_bounds__(256) void q_kernel(
    const float* __restrict__ x, const float* __restrict__ bev_grid,
    const float* __restrict__ bev_w, const float* __restrict__ bev_b,
    const float* __restrict__ c_embed,
    const float* __restrict__ q_ln_g, const float* __restrict__ q_ln_b,
    const float* __restrict__ q_b,
    const unsigned short* __restrict__ wp,
    unsigned short* __restrict__ qhb)
{
  int blk = blockIdx.x;
  int bn = blk >> 5, qt = blk & 31;
  int p0 = qt * 32;
  int b = bn / NN;
  int t = threadIdx.x;

  __shared__ unsigned short sQ[32*128];
  __shared__ float sRedQ[3][8][32];

  // ---- phase A: thread (q = t&31, og = t>>5) handles 16 o's for one query ----
  {
    int q = t & 31, og = t >> 5;
    int qi = p0 + q;
    float gx = bev_grid[qi], gy = bev_grid[QQ + qi];
    float be[16]; float ss = 0.f;
#pragma unroll
    for (int j = 0; j < 16; ++j) {
      int o = og*16 + j;
      float we = bev_w[o*2+0]*gx + bev_w[o*2+1]*gy + bev_b[o];
      float v = we - c_embed[bn*128 + o];
      be[j] = v; ss += v*v;
    }
    sRedQ[0][og][q] = ss;
    __syncthreads();
    float sst = 0.f;
#pragma unroll
    for (int g = 0; g < 8; ++g) sst += sRedQ[0][g][q];
    float rinv = 1.f/(sqrtf(sst) + 1e-7f);
    float s1 = 0.f, s2 = 0.f;
#pragma unroll
    for (int j = 0; j < 16; ++j) {
      int o = og*16 + j;
      float qv = be[j]*rinv + x[((size_t)(b*128 + o))*QQ + qi];
      be[j] = qv; s1 += qv; s2 += qv*qv;
    }
    sRedQ[1][og][q] = s1; sRedQ[2][og][q] = s2;
    __syncthreads();
    float s1t = 0.f, s2t = 0.f;
#pragma unroll
    for (int g = 0; g < 8; ++g) { s1t += sRedQ[1][g][q]; s2t += sRedQ[2][g][q]; }
    float mu = s1t*(1.f/128.f);
    float rs = rsqrtf(s2t*(1.f/128.f) - mu*mu + EPSF);
    int swz = (q & 7) << 3;
#pragma unroll
    for (int u = 0; u < 4; ++u) {
      int ob = og*16 + 4*u;
      float4 qg = *(const float4*)(q_ln_g + ob);
      float4 qb2 = *(const float4*)(q_ln_b + ob);
      *(ushort4*)&sQ[q*128 + (ob ^ swz)] = make_ushort4(
        f2bf((be[4*u+0]-mu)*rs*qg.x + qb2.x), f2bf((be[4*u+1]-mu)*rs*qg.y + qb2.y),
        f2bf((be[4*u+2]-mu)*rs*qg.z + qb2.z), f2bf((be[4*u+3]-mu)*rs*qg.w + qb2.w));
    }
  }
  __syncthreads();

  // ---- GEMM: qh = q_w^T(scaled) @ qn + q_b*scale ----
  {
    int wvv = t >> 6, l = t & 63, lo = l & 31, hi = l >> 5;
    const unsigned short* wq = wp + (size_t)4*16384 + (32*wvv + lo)*128 + hi*8;
    int swz = (lo & 7) << 3;
    f32x16 acc = {};
#pragma unroll
    for (int s = 0; s < 8; ++s) {
      int cbase = s*16 + hi*8;
      bf16x8 a0 = *(const bf16x8*)(wq + s*16);
      bf16x8 b0 = *(const bf16x8*)&sQ[lo*128 + (cbase ^ swz)];
      acc = __builtin_amdgcn_mfma_f32_32x32x16_bf16(a0, b0, acc, 0, 0, 0);
    }
    unsigned short* qrow = qhb + ((size_t)bn*QQ + p0 + lo)*128;
#pragma unroll
    for (int g = 0; g < 4; ++g) {
      int ob = 32*wvv + 8*g + 4*hi;
      float4 qb4 = *(const float4*)(q_b + ob);
      *(ushort4*)(qrow + ob) = make_ushort4(
        f2bf(acc[4*g+0] + qb4.x*QSCALE), f2bf(acc[4*g+1] + qb4.y*QSCALE),
        f2bf(acc[4*g+2] + qb4.z*QSCALE), f2bf(acc[4*g+3] + qb4.w*QSCALE));
    }
  }
}

// --- MFMA flash attention partials. block = (b, qt32, n, sp); wave = head.
__global__ __launch_bounds__(256) void attn_kernel(
    const unsigned short* __restrict__ qhb, const unsigned short* __restrict__ khb,
    const unsigned short* __restrict__ vtb,
    float* __restrict__ lsum, float* __restrict__ pacc)
{
  int blk = blockIdx.x;
  int sp = blk % SPLIT; blk /= SPLIT;
  int n  = blk % NN;    blk /= NN;
  int qt = blk % 32;    blk /= 32;
  int b  = blk;
  int t = threadIdx.x;
  int wave = t >> 6;
  int l = t & 63;
  int lo = l & 31;
  int hi = l >> 5;
  int dho = wave * 32;
  int bn = b*NN + n;

  const unsigned short* qrow = qhb + ((size_t)bn*QQ + qt*32 + lo)*128 + dho + hi*8;
  bf16x8 qf0 = *(const bf16x8*)(qrow);
  bf16x8 qf1 = *(const bf16x8*)(qrow + 16);

  f32x16 acc = {};
  float lrun = 0.f;

  int k0 = sp * KCHUNK;
  int kend = k0 + KCHUNK;

  const unsigned short* kbase = khb + (size_t)bn*KPIX*128 + dho + hi*8;
  const unsigned short* vrow  = vtb + ((size_t)bn*128 + dho + lo)*KPIX;

  for (int K0 = k0; K0 < kend; K0 += 32) {
    const unsigned short* krow = kbase + (size_t)(K0 + lo)*128;
    bf16x8 kf0 = *(const bf16x8*)(krow);
    bf16x8 kf1 = *(const bf16x8*)(krow + 16);
    bf16x8 vf0 = *(const bf16x8*)(vrow + K0 + hi*8);
    bf16x8 vf1 = *(const bf16x8*)(vrow + K0 + 16 + hi*8);

    f32x16 s = {};
    s = __builtin_amdgcn_mfma_f32_32x32x16_bf16(kf0, qf0, s, 0, 0, 0);
    s = __builtin_amdgcn_mfma_f32_32x32x16_bf16(kf1, qf1, s, 0, 0, 0);

    float p[16];
    if (K0 + 32 <= kend) {
#pragma unroll
      for (int r = 0; r < 16; ++r) { float e = __expf(s[r]); p[r] = e; lrun += e; }
    } else {
#pragma unroll
      for (int r = 0; r < 16; ++r) {
        int key = K0 + (r&3) + 8*(r>>2) + 4*hi;
        float e = (key < kend) ? __expf(s[r]) : 0.f;
        p[r] = e; lrun += e;
      }
    }

#pragma unroll
    for (int ks = 0; ks < 2; ++ks) {
      int rb = ks*8;
      unsigned a0 = pk_bf16(p[rb+0], p[rb+1]);
      unsigned c0 = pk_bf16(p[rb+2], p[rb+3]);
      unsigned b0 = pk_bf16(p[rb+4], p[rb+5]);
      unsigned d0 = pk_bf16(p[rb+6], p[rb+7]);
      unsigned sa = (unsigned)__shfl_xor((int)a0, 32);
      unsigned sc = (unsigned)__shfl_xor((int)c0, 32);
      unsigned sb = (unsigned)__shfl_xor((int)b0, 32);
      unsigned sd = (unsigned)__shfl_xor((int)d0, 32);
      union { unsigned u[4]; bf16x8 v; } pa;
      pa.u[0] = hi ? sb : a0;
      pa.u[1] = hi ? sd : c0;
      pa.u[2] = hi ? b0 : sa;
      pa.u[3] = hi ? d0 : sc;
      acc = __builtin_amdgcn_mfma_f32_32x32x16_bf16(pa.v, ks ? vf1 : vf0, acc, 0, 0, 0);
    }
  }

  float ltot = lrun + __shfl_xor(lrun, 32);
  int j = n*SPLIT + sp;
  size_t hb = ((size_t)(b*4 + wave)*NPART + j)*QQ;
  if (hi == 0) lsum[hb + qt*32 + lo] = ltot;
#pragma unroll
  for (int r = 0; r < 16; ++r) {
    int crow = (r&3) + 8*(r>>2) + 4*hi;
    pacc[(hb + qt*32 + crow)*32 + lo] = acc[r];
  }
}

// --- combine partials + proj + skip + preLN + MLP(gelu) + postLN + transposed store
__global__ __launch_bounds__(128) void epi_kernel(
    const float* __restrict__ lsum, const float* __restrict__ pacc,
    const float* __restrict__ x,
    const float* __restrict__ proj_w, const float* __restrict__ proj_b,
    const float* __restrict__ pre_g, const float* __restrict__ pre_b,
    const float* __restrict__ mlp_w1, const float* __restrict__ mlp_b1,
    const float* __restrict__ mlp_w2, const float* __restrict__ mlp_b2,
    const float* __restrict__ post_g, const float* __restrict__ post_b,
    float* __restrict__ out)
{
  int blk = blockIdx.x;
  int b = blk / QQ, q = blk % QQ;
  int t = threadIdx.x;
  int d = t & 31, m = t >> 5;
  __shared__ float s_a[128], s_z[128], s_h[256], s_red[2];

  size_t hb = (size_t)(b*4 + m)*NPART*QQ;
  float lt = 0.f, av = 0.f;
#pragma unroll 4
  for (int j = 0; j < NPART; ++j) {
    lt += lsum[hb + (size_t)j*QQ + q];
    av += pacc[(hb + (size_t)j*QQ + q)*32 + d];
  }
  s_a[t] = av / lt;
  __syncthreads();

  float z = proj_b[t] + x[((size_t)b*128 + t)*QQ + q];
#pragma unroll 8
  for (int i = 0; i < 128; ++i) z += s_a[i]*proj_w[i*128 + t];
  float mu = blk_sum128(z, s_red, t)*(1.f/128.f);
  float dv = z - mu;
  float var = blk_sum128(dv*dv, s_red, t)*(1.f/128.f);
  float zn = dv*rsqrtf(var + EPSF)*pre_g[t] + pre_b[t];
  s_z[t] = zn;
  __syncthreads();
  float h0 = mlp_b1[t], h1 = mlp_b1[t+128];
#pragma unroll 8
  for (int o = 0; o < 128; ++o) {
    float zo = s_z[o];
    h0 += zo*mlp_w1[o*256 + t];
    h1 += zo*mlp_w1[o*256 + t + 128];
  }
  s_h[t]     = 0.5f*h0*(1.f + erff(h0*0.7071067811865476f));
  s_h[t+128] = 0.5f*h1*(1.f + erff(h1*0.7071067811865476f));
  __syncthreads();
  float mo = mlp_b2[t];
#pragma unroll 8
  for (int hh = 0; hh < 256; ++hh) mo += s_h[hh]*mlp_w2[hh*128 + t];
  float z2 = zn + mo;
  mu = blk_sum128(z2, s_red, t)*(1.f/128.f);
  dv = z2 - mu;
  var = blk_sum128(dv*dv, s_red, t)*(1.f/128.f);
  float o2 = dv*rsqrtf(var + EPSF)*post_g[t] + post_b[t];
  out[((size_t)b*128 + t)*QQ + q] = o2;
}

extern "C" void kernel_launch(void* const* d_in, const int* in_sizes, int n_in,
                              void* d_out, int out_size, void* d_ws, size_t ws_size,
                              hipStream_t stream) {
  const float* x           = (const float*)d_in[0];
  const float* feature     = (const float*)d_in[1];
  const float* I_inv       = (const float*)d_in[2];
  const float* E_inv       = (const float*)d_in[3];
  const float* bev_grid    = (const float*)d_in[4];
  const float* image_plane = (const float*)d_in[5];
  const float* fl_bn_g = (const float*)d_in[6];
  const float* fl_bn_b = (const float*)d_in[7];
  const float* fl_bn_m = (const float*)d_in[8];
  const float* fl_bn_v = (const float*)d_in[9];
  const float* fl_w    = (const float*)d_in[10];
  const float* fp_bn_g = (const float*)d_in[11];
  const float* fp_bn_b = (const float*)d_in[12];
  const float* fp_bn_m = (const float*)d_in[13];
  const float* fp_bn_v = (const float*)d_in[14];
  const float* fp_w    = (const float*)d_in[15];
  const float* bev_w   = (const float*)d_in[16];
  const float* bev_b   = (const float*)d_in[17];
  const float* img_w   = (const float*)d_in[18];
  const float* cam_w   = (const float*)d_in[19];
  const float* q_ln_g  = (const float*)d_in[20];
  const float* q_ln_b  = (const float*)d_in[21];
  const float* q_w     = (const float*)d_in[22];
  const float* q_b     = (const float*)d_in[23];
  const float* k_ln_g  = (const float*)d_in[24];
  const float* k_ln_b  = (const float*)d_in[25];
  const float* k_w     = (const float*)d_in[26];
  const float* k_b     = (const float*)d_in[27];
  const float* v_ln_g  = (const float*)d_in[28];
  const float* v_ln_b  = (const float*)d_in[29];
  const float* v_w     = (const float*)d_in[30];
  const float* v_b     = (const float*)d_in[31];
  const float* proj_w  = (const float*)d_in[32];
  const float* proj_b  = (const float*)d_in[33];
  const float* pre_g   = (const float*)d_in[34];
  const float* pre_b   = (const float*)d_in[35];
  const float* mlp_w1  = (const float*)d_in[36];
  const float* mlp_b1  = (const float*)d_in[37];
  const float* mlp_w2  = (const float*)d_in[38];
  const float* mlp_b2  = (const float*)d_in[39];
  const float* post_g  = (const float*)d_in[40];
  const float* post_b  = (const float*)d_in[41];

  // workspace layout: f32 buffers first, then 16B-aligned bf16 buffers
  float* ws = (float*)d_ws;
  float* c_embed = ws;                                        // 1536
  float* lsum = ws + 1536;                                    // 2*4*24*1024
  float* pacc = lsum + (size_t)BB*4*NPART*QQ;                 // *32
  unsigned short* qhb = (unsigned short*)(pacc + (size_t)BB*4*NPART*QQ*32);
  unsigned short* khb = qhb + (size_t)BB*NN*QQ*128;
  unsigned short* vtb = khb + (size_t)BB*NN*KPIX*128;
  unsigned short* wpk = vtb + (size_t)BB*NN*KPIX*128;         // 5*16384 bf16
  float* out = (float*)d_out;

  hipLaunchKernelGGL(prepack_kernel, dim3(5*128), dim3(128), 0, stream,
                     fp_w, fl_w, k_w, v_w, q_w, wpk);
  hipLaunchKernelGGL(ce_kernel, dim3(BB*NN), dim3(128), 0, stream, cam_w, E_inv, c_embed);
  hipLaunchKernelGGL(kv_kernel, dim3(BB*NN*NTILE_KV), dim3(256), 0, stream,
                     feature, I_inv, E_inv, image_plane, c_embed, img_w,
                     fp_bn_g, fp_bn_b, fp_bn_m, fp_bn_v,
                     fl_bn_g, fl_bn_b, fl_bn_m, fl_bn_v,
                     k_ln_g, k_ln_b, k_b,
                     v_ln_g, v_ln_b, v_b,
                     wpk, khb, vtb);
  hipLaunchKernelGGL(q_kernel, dim3(BB*NN*32), dim3(256), 0, stream,
                     x, bev_grid, bev_w, bev_b, c_embed,
                     q_ln_g, q_ln_b, q_b, wpk, qhb);
  hipLaunchKernelGGL(attn_kernel, dim3(BB*32*NN*SPLIT), dim3(256), 0, stream,
                     qhb, khb, vtb, lsum, pacc);
  hipLaunchKernelGGL(epi_kernel, dim3(BB*QQ), dim3(128), 0, stream,
                     lsum, pacc, x, proj_w, proj_b, pre_g, pre_b,
                     mlp_w1, mlp_b1, mlp_w2, mlp_b2, post_g, post_b, out);
}

// Round 5
// 87.129 us; speedup vs baseline: 11.5315x; 1.3030x over previous
//
#include <hip/hip_runtime.h>
#include <math.h>

#define EPSF 1e-5f

// problem sizes
#define BB 2
#define NN 6
#define KPIX 1680      // 28*60
#define QQ 1024        // 32*32
#define SPLIT 4
#define KCHUNK (KPIX/SPLIT)   // 420
#define NPART (NN*SPLIT)      // 24
#define QSCALE 0.17677669529663687f  // 32^-0.5
#define NTILE_KV 53    // ceil(1680/32)

// prepacked weight offsets (bf16 elements)
#define WOFF_FP   0
#define WOFF_FL   16384
#define WOFF_K    32768
#define WOFF_V    49152
#define WOFF_Q    65536
#define WOFF_PROJ 81920
#define WOFF_W1   98304
#define WOFF_W2   131072
#define WPK_ELEMS 163840

typedef __attribute__((ext_vector_type(8))) short bf16x8;
typedef __attribute__((ext_vector_type(16))) float f32x16;

__device__ __forceinline__ unsigned short f2bf(float f) {
  union { float f; unsigned u; } v; v.f = f;
  unsigned r = v.u + 0x7FFFu + ((v.u >> 16) & 1u);   // RNE
  return (unsigned short)(r >> 16);
}
__device__ __forceinline__ float bf2f(unsigned short u) {
  union { unsigned u; float f; } v; v.u = ((unsigned)u) << 16; return v.f;
}
__device__ __forceinline__ unsigned pk_bf16(float lo, float hi) {
  unsigned r;
  asm volatile("v_cvt_pk_bf16_f32 %0, %1, %2" : "=v"(r) : "v"(lo), "v"(hi));
  return r;
}
// half_swap: a' = [a.lo32 | b.lo32], b' = [a.hi32 | b.hi32]
__device__ __forceinline__ void half_swap(unsigned &a, unsigned &b) {
#if __has_builtin(__builtin_amdgcn_permlane32_swap)
  auto r = __builtin_amdgcn_permlane32_swap(a, b, false, false);
  a = (unsigned)r[0]; b = (unsigned)r[1];
#else
  unsigned sa = (unsigned)__shfl_xor((int)a, 32);
  unsigned sb = (unsigned)__shfl_xor((int)b, 32);
  int hi = (threadIdx.x & 63) >> 5;
  unsigned na = hi ? sb : a;
  unsigned nb = hi ? b : sa;
  a = na; b = nb;
#endif
}

// --- weight prepack to bf16 fragment-friendly layouts
__global__ void prepack_kernel(const float* __restrict__ fp_w, const float* __restrict__ fl_w,
                               const float* __restrict__ k_w, const float* __restrict__ v_w,
                               const float* __restrict__ q_w, const float* __restrict__ proj_w,
                               const float* __restrict__ mlp_w1, const float* __restrict__ mlp_w2,
                               unsigned short* __restrict__ wp) {
  int blk = blockIdx.x;
  int c = threadIdx.x;
  if (blk < 640) {
    int mat = blk >> 7, o = blk & 127;
    float v;
    if (mat == 0)      v = fp_w[o*128 + c];
    else if (mat == 1) v = fl_w[o*128 + c];
    else if (mat == 2) v = k_w[c*128 + o];
    else if (mat == 3) v = v_w[c*128 + o];
    else               v = q_w[c*128 + o] * QSCALE;
    wp[(size_t)mat*16384 + o*128 + c] = f2bf(v);
  } else if (blk < 768) {
    int row = blk - 640;                         // proj^T [o][i]
    wp[WOFF_PROJ + row*128 + c] = f2bf(proj_w[c*128 + row]);
  } else if (blk < 1024) {
    int row = blk - 768;                         // w1^T [h][i]
    wp[WOFF_W1 + row*128 + c] = f2bf(mlp_w1[c*256 + row]);
  } else {
    int i2 = blk - 1024;                         // w2^T [o][h]
    int row = i2 >> 1, col = (i2 & 1)*128 + c;
    wp[WOFF_W2 + row*256 + col] = f2bf(mlp_w2[col*128 + row]);
  }
}

// --- camera-center embedding
__global__ void ce_kernel(const float* __restrict__ cam_w, const float* __restrict__ E_inv,
                          float* __restrict__ c_embed) {
  int bn = blockIdx.x; int t = threadIdx.x;
  const float* E = E_inv + bn * 16;
  float s = cam_w[t*4+0]*E[3] + cam_w[t*4+1]*E[7] + cam_w[t*4+2]*E[11] + cam_w[t*4+3]*E[15];
  c_embed[bn*128 + t] = s;
}

// --- MFMA kv (unchanged from round 4)
__global__ __launch_bounds__(256) void kv_kernel(
    const float* __restrict__ feature, const float* __restrict__ I_inv,
    const float* __restrict__ E_inv, const float* __restrict__ image_plane,
    const float* __restrict__ c_embed, const float* __restrict__ img_w,
    const float* __restrict__ fp_bn_g, const float* __restrict__ fp_bn_b,
    const float* __restrict__ fp_bn_m, const float* __restrict__ fp_bn_v,
    const float* __restrict__ fl_bn_g, const float* __restrict__ fl_bn_b,
    const float* __restrict__ fl_bn_m, const float* __restrict__ fl_bn_v,
    const float* __restrict__ k_ln_g, const float* __restrict__ k_ln_b,
    const float* __restrict__ k_b,
    const float* __restrict__ v_ln_g, const float* __restrict__ v_ln_b,
    const float* __restrict__ v_b,
    const unsigned short* __restrict__ wp,
    unsigned short* __restrict__ khb, unsigned short* __restrict__ vtb)
{
  int blk = blockIdx.x;
  int bn = blk / NTILE_KV, tp = blk % NTILE_KV;
  int p0 = tp * 32;
  int t = threadIdx.x;
  int wv = t >> 6, l = t & 63, lo = l & 31, hi = l >> 5;

  __shared__ unsigned short sA[2][32*128];
  __shared__ float sD[4][32];
  __shared__ float sRed[5][4][32];

  if (t < 32) {
    int pix = min(p0 + t, KPIX-1);
    const float* Ii = I_inv + bn*9;
    const float* Ei = E_inv + bn*16;
    float px = image_plane[pix], py = image_plane[KPIX + pix], pz = image_plane[2*KPIX + pix];
    float c0 = Ii[0]*px + Ii[1]*py + Ii[2]*pz;
    float c1 = Ii[3]*px + Ii[4]*py + Ii[5]*pz;
    float c2 = Ii[6]*px + Ii[7]*py + Ii[8]*pz;
    sD[0][t] = Ei[0]*c0 + Ei[1]*c1 + Ei[2]*c2  + Ei[3];
    sD[1][t] = Ei[4]*c0 + Ei[5]*c1 + Ei[6]*c2  + Ei[7];
    sD[2][t] = Ei[8]*c0 + Ei[9]*c1 + Ei[10]*c2 + Ei[11];
    sD[3][t] = Ei[12]*c0 + Ei[13]*c1 + Ei[14]*c2 + Ei[15];
  }

  {
    int c = t >> 1, ph = t & 1;
    float gp = fp_bn_g[c]*rsqrtf(fp_bn_v[c]+EPSF); float bp = fp_bn_b[c] - fp_bn_m[c]*gp;
    float gl = fl_bn_g[c]*rsqrtf(fl_bn_v[c]+EPSF); float bl = fl_bn_b[c] - fl_bn_m[c]*gl;
    const float* frow = feature + ((size_t)bn*128 + c)*KPIX;
#pragma unroll
    for (int i = 0; i < 4; ++i) {
      int plb = ph*16 + 4*i;
      int pix = p0 + plb;
      float4 f;
      if (pix + 3 < KPIX) f = *(const float4*)(frow + pix);
      else {
        f.x = frow[min(pix+0, KPIX-1)]; f.y = frow[min(pix+1, KPIX-1)];
        f.z = frow[min(pix+2, KPIX-1)]; f.w = frow[min(pix+3, KPIX-1)];
      }
      float fv[4] = {f.x, f.y, f.z, f.w};
#pragma unroll
      for (int j = 0; j < 4; ++j) {
        int pl = plb + j;
        int cc = c ^ ((pl & 7) << 3);
        sA[0][pl*128 + cc] = f2bf(fmaxf(fv[j]*gp + bp, 0.f));
        sA[1][pl*128 + cc] = f2bf(fmaxf(fv[j]*gl + bl, 0.f));
      }
    }
  }
  __syncthreads();

  f32x16 acck = {}, accv = {};
  {
    const unsigned short* wfp = wp + WOFF_FP + (32*wv + lo)*128 + hi*8;
    const unsigned short* wfl = wp + WOFF_FL + (32*wv + lo)*128 + hi*8;
    int swz = (lo & 7) << 3;
#pragma unroll
    for (int s = 0; s < 8; ++s) {
      int cbase = s*16 + hi*8;
      bf16x8 a0 = *(const bf16x8*)(wfp + s*16);
      bf16x8 a1 = *(const bf16x8*)(wfl + s*16);
      bf16x8 b0 = *(const bf16x8*)&sA[0][lo*128 + (cbase ^ swz)];
      bf16x8 b1 = *(const bf16x8*)&sA[1][lo*128 + (cbase ^ swz)];
      acck = __builtin_amdgcn_mfma_f32_32x32x16_bf16(a0, b0, acck, 0, 0, 0);
      accv = __builtin_amdgcn_mfma_f32_32x32x16_bf16(a1, b1, accv, 0, 0, 0);
    }
  }

  float d0 = sD[0][lo], d1 = sD[1][lo], d2 = sD[2][lo], d3 = sD[3][lo];

  float ime[16];
  float ss = 0.f, vs1 = 0.f, vs2 = 0.f;
#pragma unroll
  for (int r = 0; r < 16; ++r) {
    int o = 32*wv + (r&3) + 8*(r>>2) + 4*hi;
    float4 iw = *(const float4*)(img_w + o*4);
    float de = iw.x*d0 + iw.y*d1 + iw.z*d2 + iw.w*d3 - c_embed[bn*128 + o];
    ime[r] = de; ss += de*de;
    float vv = accv[r];
    vs1 += vv; vs2 += vv*vv;
  }
  ss  += __shfl_xor(ss, 32);
  vs1 += __shfl_xor(vs1, 32);
  vs2 += __shfl_xor(vs2, 32);
  if (hi == 0) { sRed[0][wv][lo] = ss; sRed[1][wv][lo] = vs1; sRed[2][wv][lo] = vs2; }
  __syncthreads();
  float sst  = sRed[0][0][lo]+sRed[0][1][lo]+sRed[0][2][lo]+sRed[0][3][lo];
  float vs1t = sRed[1][0][lo]+sRed[1][1][lo]+sRed[1][2][lo]+sRed[1][3][lo];
  float vs2t = sRed[2][0][lo]+sRed[2][1][lo]+sRed[2][2][lo]+sRed[2][3][lo];
  float rinv = 1.f/(sqrtf(sst) + 1e-7f);
  float vmu = vs1t*(1.f/128.f);
  float vrs = rsqrtf(vs2t*(1.f/128.f) - vmu*vmu + EPSF);

  float kval[16];
  float ks1 = 0.f, ks2 = 0.f;
#pragma unroll
  for (int r = 0; r < 16; ++r) {
    float kv2 = acck[r] + ime[r]*rinv;
    kval[r] = kv2; ks1 += kv2; ks2 += kv2*kv2;
  }
  ks1 += __shfl_xor(ks1, 32);
  ks2 += __shfl_xor(ks2, 32);
  if (hi == 0) { sRed[3][wv][lo] = ks1; sRed[4][wv][lo] = ks2; }
  __syncthreads();
  float ks1t = sRed[3][0][lo]+sRed[3][1][lo]+sRed[3][2][lo]+sRed[3][3][lo];
  float ks2t = sRed[4][0][lo]+sRed[4][1][lo]+sRed[4][2][lo]+sRed[4][3][lo];
  float kmu = ks1t*(1.f/128.f);
  float krs = rsqrtf(ks2t*(1.f/128.f) - kmu*kmu + EPSF);

  {
    int swz = (lo & 7) << 3;
#pragma unroll
    for (int g = 0; g < 4; ++g) {
      int ob = 32*wv + 8*g + 4*hi;
      float4 kg = *(const float4*)(k_ln_g + ob);
      float4 kb2 = *(const float4*)(k_ln_b + ob);
      float4 vg = *(const float4*)(v_ln_g + ob);
      float4 vb2 = *(const float4*)(v_ln_b + ob);
      float kn0 = (kval[4*g+0]-kmu)*krs*kg.x + kb2.x;
      float kn1 = (kval[4*g+1]-kmu)*krs*kg.y + kb2.y;
      float kn2 = (kval[4*g+2]-kmu)*krs*kg.z + kb2.z;
      float kn3 = (kval[4*g+3]-kmu)*krs*kg.w + kb2.w;
      float vn0 = (accv[4*g+0]-vmu)*vrs*vg.x + vb2.x;
      float vn1 = (accv[4*g+1]-vmu)*vrs*vg.y + vb2.y;
      float vn2 = (accv[4*g+2]-vmu)*vrs*vg.z + vb2.z;
      float vn3 = (accv[4*g+3]-vmu)*vrs*vg.w + vb2.w;
      int idx = lo*128 + (ob ^ swz);
      *(ushort4*)&sA[0][idx] = make_ushort4(f2bf(kn0), f2bf(kn1), f2bf(kn2), f2bf(kn3));
      *(ushort4*)&sA[1][idx] = make_ushort4(f2bf(vn0), f2bf(vn1), f2bf(vn2), f2bf(vn3));
    }
  }
  __syncthreads();

  f32x16 a2k = {}, a2v = {};
  {
    const unsigned short* wk = wp + WOFF_K + (32*wv + lo)*128 + hi*8;
    const unsigned short* wv2 = wp + WOFF_V + (32*wv + lo)*128 + hi*8;
    int swz = (lo & 7) << 3;
#pragma unroll
    for (int s = 0; s < 8; ++s) {
      int cbase = s*16 + hi*8;
      bf16x8 a0 = *(const bf16x8*)(wk + s*16);
      bf16x8 a1 = *(const bf16x8*)(wv2 + s*16);
      bf16x8 b0 = *(const bf16x8*)&sA[0][lo*128 + (cbase ^ swz)];
      bf16x8 b1 = *(const bf16x8*)&sA[1][lo*128 + (cbase ^ swz)];
      a2k = __builtin_amdgcn_mfma_f32_32x32x16_bf16(a0, b0, a2k, 0, 0, 0);
      a2v = __builtin_amdgcn_mfma_f32_32x32x16_bf16(a1, b1, a2v, 0, 0, 0);
    }
  }

  int pix = p0 + lo;
  if (pix < KPIX) {
    unsigned short* krow = khb + ((size_t)bn*KPIX + pix)*128;
#pragma unroll
    for (int g = 0; g < 4; ++g) {
      int ob = 32*wv + 8*g + 4*hi;
      float4 kb4 = *(const float4*)(k_b + ob);
      *(ushort4*)(krow + ob) = make_ushort4(
        f2bf(a2k[4*g+0] + kb4.x), f2bf(a2k[4*g+1] + kb4.y),
        f2bf(a2k[4*g+2] + kb4.z), f2bf(a2k[4*g+3] + kb4.w));
      float4 vb4 = *(const float4*)(v_b + ob);
      vtb[((size_t)bn*128 + ob+0)*KPIX + pix] = f2bf(a2v[4*g+0] + vb4.x);
      vtb[((size_t)bn*128 + ob+1)*KPIX + pix] = f2bf(a2v[4*g+1] + vb4.y);
      vtb[((size_t)bn*128 + ob+2)*KPIX + pix] = f2bf(a2v[4*g+2] + vb4.z);
      vtb[((size_t)bn*128 + ob+3)*KPIX + pix] = f2bf(a2v[4*g+3] + vb4.w);
    }
  }
}

// --- MFMA q (unchanged from round 4)
__global__ __launch_bounds__(256) void q_kernel(
    const float* __restrict__ x, const float* __restrict__ bev_grid,
    const float* __restrict__ bev_w, const float* __restrict__ bev_b,
    const float* __restrict__ c_embed,
    const float* __restrict__ q_ln_g, const float* __restrict__ q_ln_b,
    const float* __restrict__ q_b,
    const unsigned short* __restrict__ wp,
    unsigned short* __restrict__ qhb)
{
  int blk = blockIdx.x;
  int bn = blk >> 5, qt = blk & 31;
  int p0 = qt * 32;
  int b = bn / NN;
  int t = threadIdx.x;

  __shared__ unsigned short sQ[32*128];
  __shared__ float sRedQ[3][8][32];

  {
    int q = t & 31, og = t >> 5;
    int qi = p0 + q;
    float gx = bev_grid[qi], gy = bev_grid[QQ + qi];
    float be[16]; float ss = 0.f;
#pragma unroll
    for (int j = 0; j < 16; ++j) {
      int o = og*16 + j;
      float we = bev_w[o*2+0]*gx + bev_w[o*2+1]*gy + bev_b[o];
      float v = we - c_embed[bn*128 + o];
      be[j] = v; ss += v*v;
    }
    sRedQ[0][og][q] = ss;
    __syncthreads();
    float sst = 0.f;
#pragma unroll
    for (int g = 0; g < 8; ++g) sst += sRedQ[0][g][q];
    float rinv = 1.f/(sqrtf(sst) + 1e-7f);
    float s1 = 0.f, s2 = 0.f;
#pragma unroll
    for (int j = 0; j < 16; ++j) {
      int o = og*16 + j;
      float qv = be[j]*rinv + x[((size_t)(b*128 + o))*QQ + qi];
      be[j] = qv; s1 += qv; s2 += qv*qv;
    }
    sRedQ[1][og][q] = s1; sRedQ[2][og][q] = s2;
    __syncthreads();
    float s1t = 0.f, s2t = 0.f;
#pragma unroll
    for (int g = 0; g < 8; ++g) { s1t += sRedQ[1][g][q]; s2t += sRedQ[2][g][q]; }
    float mu = s1t*(1.f/128.f);
    float rs = rsqrtf(s2t*(1.f/128.f) - mu*mu + EPSF);
    int swz = (q & 7) << 3;
#pragma unroll
    for (int u = 0; u < 4; ++u) {
      int ob = og*16 + 4*u;
      float4 qg = *(const float4*)(q_ln_g + ob);
      float4 qb2 = *(const float4*)(q_ln_b + ob);
      *(ushort4*)&sQ[q*128 + (ob ^ swz)] = make_ushort4(
        f2bf((be[4*u+0]-mu)*rs*qg.x + qb2.x), f2bf((be[4*u+1]-mu)*rs*qg.y + qb2.y),
        f2bf((be[4*u+2]-mu)*rs*qg.z + qb2.z), f2bf((be[4*u+3]-mu)*rs*qg.w + qb2.w));
    }
  }
  __syncthreads();

  {
    int wvv = t >> 6, l = t & 63, lo = l & 31, hi = l >> 5;
    const unsigned short* wq = wp + WOFF_Q + (32*wvv + lo)*128 + hi*8;
    int swz = (lo & 7) << 3;
    f32x16 acc = {};
#pragma unroll
    for (int s = 0; s < 8; ++s) {
      int cbase = s*16 + hi*8;
      bf16x8 a0 = *(const bf16x8*)(wq + s*16);
      bf16x8 b0 = *(const bf16x8*)&sQ[lo*128 + (cbase ^ swz)];
      acc = __builtin_amdgcn_mfma_f32_32x32x16_bf16(a0, b0, acc, 0, 0, 0);
    }
    unsigned short* qrow = qhb + ((size_t)bn*QQ + p0 + lo)*128;
#pragma unroll
    for (int g = 0; g < 4; ++g) {
      int ob = 32*wvv + 8*g + 4*hi;
      float4 qb4 = *(const float4*)(q_b + ob);
      *(ushort4*)(qrow + ob) = make_ushort4(
        f2bf(acc[4*g+0] + qb4.x*QSCALE), f2bf(acc[4*g+1] + qb4.y*QSCALE),
        f2bf(acc[4*g+2] + qb4.z*QSCALE), f2bf(acc[4*g+3] + qb4.w*QSCALE));
    }
  }
}

// --- MFMA flash attention partials. block = (b, qt64, n, sp); wave = head, 64 q/block.
__global__ __launch_bounds__(256) void attn_kernel(
    const unsigned short* __restrict__ qhb, const unsigned short* __restrict__ khb,
    const unsigned short* __restrict__ vtb,
    float* __restrict__ lsum, unsigned short* __restrict__ pacb)
{
  int blk = blockIdx.x;
  int sp = blk % SPLIT; blk /= SPLIT;
  int n  = blk % NN;    blk /= NN;
  int qt = blk % 16;    blk /= 16;
  int b  = blk;
  int t = threadIdx.x;
  int wave = t >> 6, l = t & 63, lo = l & 31, hi = l >> 5;
  int dho = wave * 32;
  int bn = b*NN + n;

  bf16x8 qf[2][2];
#pragma unroll
  for (int g = 0; g < 2; ++g) {
    const unsigned short* qrow = qhb + ((size_t)bn*QQ + qt*64 + g*32 + lo)*128 + dho + hi*8;
    qf[g][0] = *(const bf16x8*)(qrow);
    qf[g][1] = *(const bf16x8*)(qrow + 16);
  }

  f32x16 acc[2] = {};
  float lr[2] = {0.f, 0.f};

  int k0 = sp * KCHUNK, kend = k0 + KCHUNK;
  const unsigned short* kbase = khb + (size_t)bn*KPIX*128 + dho + hi*8;
  const unsigned short* vrow  = vtb + ((size_t)bn*128 + dho + lo)*KPIX;

  for (int K0 = k0; K0 < kend; K0 += 32) {
    const unsigned short* krow = kbase + (size_t)(K0 + lo)*128;
    bf16x8 kf0 = *(const bf16x8*)(krow);
    bf16x8 kf1 = *(const bf16x8*)(krow + 16);
    bf16x8 vf0 = *(const bf16x8*)(vrow + K0 + hi*8);
    bf16x8 vf1 = *(const bf16x8*)(vrow + K0 + 16 + hi*8);
    bool full = (K0 + 32 <= kend);
#pragma unroll
    for (int g = 0; g < 2; ++g) {
      f32x16 s = {};
      s = __builtin_amdgcn_mfma_f32_32x32x16_bf16(kf0, qf[g][0], s, 0, 0, 0);
      s = __builtin_amdgcn_mfma_f32_32x32x16_bf16(kf1, qf[g][1], s, 0, 0, 0);
      float p[16];
      float lsub = 0.f;
      if (full) {
#pragma unroll
        for (int r = 0; r < 16; ++r) { float e = __expf(s[r]); p[r] = e; lsub += e; }
      } else {
#pragma unroll
        for (int r = 0; r < 16; ++r) {
          int key = K0 + (r&3) + 8*(r>>2) + 4*hi;
          float e = (key < kend) ? __expf(s[r]) : 0.f;
          p[r] = e; lsub += e;
        }
      }
      lr[g] += lsub;
#pragma unroll
      for (int ks = 0; ks < 2; ++ks) {
        int rb = ks*8;
        unsigned a0 = pk_bf16(p[rb+0], p[rb+1]);
        unsigned c0 = pk_bf16(p[rb+2], p[rb+3]);
        unsigned b0 = pk_bf16(p[rb+4], p[rb+5]);
        unsigned d0 = pk_bf16(p[rb+6], p[rb+7]);
        half_swap(a0, b0);
        half_swap(c0, d0);
        union { unsigned u[4]; bf16x8 v; } pa;
        pa.u[0] = a0; pa.u[1] = c0; pa.u[2] = b0; pa.u[3] = d0;
        acc[g] = __builtin_amdgcn_mfma_f32_32x32x16_bf16(pa.v, ks ? vf1 : vf0, acc[g], 0, 0, 0);
      }
    }
  }

  size_t hb = ((size_t)(b*4 + wave)*NPART + (n*SPLIT + sp))*QQ;
#pragma unroll
  for (int g = 0; g < 2; ++g) {
    float ltot = lr[g] + __shfl_xor(lr[g], 32);
    if (hi == 0) lsum[hb + qt*64 + g*32 + lo] = ltot;
#pragma unroll
    for (int r = 0; r < 16; ++r) {
      int crow = (r&3) + 8*(r>>2) + 4*hi;
      pacb[(hb + qt*64 + g*32 + crow)*32 + lo] = f2bf(acc[g][r]);
    }
  }
}

// --- MFMA epilogue: combine + proj + skip + preLN + MLP(gelu) + postLN + store.
// block = (b, 32-query tile), 512 threads = 8 waves.
__global__ __launch_bounds__(512) void epi_kernel(
    const float* __restrict__ lsum, const unsigned short* __restrict__ pacb,
    const float* __restrict__ x, const unsigned short* __restrict__ wp,
    const float* __restrict__ proj_b,
    const float* __restrict__ pre_g, const float* __restrict__ pre_b,
    const float* __restrict__ mlp_b1, const float* __restrict__ mlp_b2,
    const float* __restrict__ post_g, const float* __restrict__ post_b,
    float* __restrict__ out)
{
  int blk = blockIdx.x;
  int b = blk >> 5, qt = blk & 31;
  int q0 = qt * 32;
  int t = threadIdx.x;
  int wv = t >> 6, l = t & 63, lo = l & 31, hi = l >> 5;
  int rt = wv & 3, kh = wv >> 2;

  __shared__ unsigned short sA[32*128];
  __shared__ unsigned short sZ[32*128];
  __shared__ unsigned short sH[32*256];
  __shared__ float sPar[4][64][16];
  __shared__ float sRedE[2][4][32];

  // ---- combine partials -> a bf16 tile [q][128] swizzled ----
  {
    int q = t & 31, g = t >> 5;              // g 0..15
    int m = g >> 2, dl = (g & 3) * 8;
    size_t basehm = ((size_t)(b*4 + m)*NPART)*QQ + q0 + q;
    float lt = 0.f;
    float av[8] = {0,0,0,0,0,0,0,0};
    for (int j = 0; j < NPART; ++j) {
      size_t base = basehm + (size_t)j*QQ;
      lt += lsum[base];
      const unsigned short* pp = pacb + base*32 + dl;
      ushort4 u0 = *(const ushort4*)(pp);
      ushort4 u1 = *(const ushort4*)(pp + 4);
      av[0] += bf2f(u0.x); av[1] += bf2f(u0.y); av[2] += bf2f(u0.z); av[3] += bf2f(u0.w);
      av[4] += bf2f(u1.x); av[5] += bf2f(u1.y); av[6] += bf2f(u1.z); av[7] += bf2f(u1.w);
    }
    float rl = 1.f / lt;
    int swz = (q & 7) << 3;
    int dg = (g*8) ^ swz;
    *(ushort4*)&sA[q*128 + dg] = make_ushort4(
      f2bf(av[0]*rl), f2bf(av[1]*rl), f2bf(av[2]*rl), f2bf(av[3]*rl));
    *(ushort4*)&sA[q*128 + dg + 4] = make_ushort4(
      f2bf(av[4]*rl), f2bf(av[5]*rl), f2bf(av[6]*rl), f2bf(av[7]*rl));
  }
  __syncthreads();

  // ---- proj GEMM (split-K over wave pairs) ----
  f32x16 acc = {};
  {
    const unsigned short* wA = wp + WOFF_PROJ + (32*rt + lo)*128 + kh*64 + hi*8;
    int swz = (lo & 7) << 3;
#pragma unroll
    for (int s = 0; s < 4; ++s) {
      int cb = kh*64 + s*16 + hi*8;
      bf16x8 a0 = *(const bf16x8*)(wA + s*16);
      bf16x8 b0 = *(const bf16x8*)&sA[lo*128 + (cb ^ swz)];
      acc = __builtin_amdgcn_mfma_f32_32x32x16_bf16(a0, b0, acc, 0, 0, 0);
    }
  }
  if (wv >= 4) {
#pragma unroll
    for (int r = 0; r < 16; ++r) sPar[wv-4][l][r] = acc[r];
  }
  __syncthreads();

  float znr[16], zv[16];
  if (wv < 4) {
    float s1 = 0.f, s2 = 0.f;
#pragma unroll
    for (int r = 0; r < 16; ++r) {
      int o = 32*rt + (r&3) + 8*(r>>2) + 4*hi;
      float z = acc[r] + sPar[wv][l][r] + proj_b[o] + x[((size_t)b*128 + o)*QQ + q0 + lo];
      zv[r] = z; s1 += z; s2 += z*z;
    }
    s1 += __shfl_xor(s1, 32); s2 += __shfl_xor(s2, 32);
    if (hi == 0) { sRedE[0][rt][lo] = s1; sRedE[1][rt][lo] = s2; }
  }
  __syncthreads();
  if (wv < 4) {
    float s1t = sRedE[0][0][lo]+sRedE[0][1][lo]+sRedE[0][2][lo]+sRedE[0][3][lo];
    float s2t = sRedE[1][0][lo]+sRedE[1][1][lo]+sRedE[1][2][lo]+sRedE[1][3][lo];
    float mu = s1t*(1.f/128.f);
    float rs = rsqrtf(s2t*(1.f/128.f) - mu*mu + EPSF);
    int swz = (lo & 7) << 3;
#pragma unroll
    for (int g2 = 0; g2 < 4; ++g2) {
      int ob = 32*rt + 8*g2 + 4*hi;
      float4 pg = *(const float4*)(pre_g + ob);
      float4 pb = *(const float4*)(pre_b + ob);
      float z0 = (zv[4*g2+0]-mu)*rs*pg.x + pb.x;
      float z1 = (zv[4*g2+1]-mu)*rs*pg.y + pb.y;
      float z2 = (zv[4*g2+2]-mu)*rs*pg.z + pb.z;
      float z3 = (zv[4*g2+3]-mu)*rs*pg.w + pb.w;
      znr[4*g2+0] = z0; znr[4*g2+1] = z1; znr[4*g2+2] = z2; znr[4*g2+3] = z3;
      *(ushort4*)&sZ[lo*128 + (ob ^ swz)] = make_ushort4(f2bf(z0), f2bf(z1), f2bf(z2), f2bf(z3));
    }
  }
  __syncthreads();

  // ---- MLP1 GEMM (8 row-tiles over 8 waves), GELU, -> sH ----
  {
    f32x16 acch = {};
    const unsigned short* wA = wp + WOFF_W1 + (32*wv + lo)*128 + hi*8;
    int swz = (lo & 7) << 3;
#pragma unroll
    for (int s = 0; s < 8; ++s) {
      int cb = s*16 + hi*8;
      bf16x8 a0 = *(const bf16x8*)(wA + s*16);
      bf16x8 b0 = *(const bf16x8*)&sZ[lo*128 + (cb ^ swz)];
      acch = __builtin_amdgcn_mfma_f32_32x32x16_bf16(a0, b0, acch, 0, 0, 0);
    }
#pragma unroll
    for (int g2 = 0; g2 < 4; ++g2) {
      int hrow = 32*wv + 8*g2 + 4*hi;
      float4 b1 = *(const float4*)(mlp_b1 + hrow);
      float h0 = acch[4*g2+0] + b1.x, h1 = acch[4*g2+1] + b1.y;
      float h2 = acch[4*g2+2] + b1.z, h3 = acch[4*g2+3] + b1.w;
      float g0 = 0.5f*h0*(1.f + erff(h0*0.7071067811865476f));
      float g1 = 0.5f*h1*(1.f + erff(h1*0.7071067811865476f));
      float g2f = 0.5f*h2*(1.f + erff(h2*0.7071067811865476f));
      float g3 = 0.5f*h3*(1.f + erff(h3*0.7071067811865476f));
      *(ushort4*)&sH[lo*256 + (hrow ^ swz)] = make_ushort4(f2bf(g0), f2bf(g1), f2bf(g2f), f2bf(g3));
    }
  }
  __syncthreads();

  // ---- MLP2 GEMM (split-K over wave pairs) ----
  f32x16 acc2 = {};
  {
    const unsigned short* wA = wp + WOFF_W2 + (32*rt + lo)*256 + kh*128 + hi*8;
    int swz = (lo & 7) << 3;
#pragma unroll
    for (int s = 0; s < 8; ++s) {
      int cb = kh*128 + s*16 + hi*8;
      bf16x8 a0 = *(const bf16x8*)(wA + s*16);
      bf16x8 b0 = *(const bf16x8*)&sH[lo*256 + (cb ^ swz)];
      acc2 = __builtin_amdgcn_mfma_f32_32x32x16_bf16(a0, b0, acc2, 0, 0, 0);
    }
  }
  if (wv >= 4) {
#pragma unroll
    for (int r = 0; r < 16; ++r) sPar[wv-4][l][r] = acc2[r];
  }
  __syncthreads();

  float z2v[16];
  if (wv < 4) {
    float s1 = 0.f, s2 = 0.f;
#pragma unroll
    for (int r = 0; r < 16; ++r) {
      int o = 32*rt + (r&3) + 8*(r>>2) + 4*hi;
      float z2 = znr[r] + acc2[r] + sPar[wv][l][r] + mlp_b2[o];
      z2v[r] = z2; s1 += z2; s2 += z2*z2;
    }
    s1 += __shfl_xor(s1, 32); s2 += __shfl_xor(s2, 32);
    if (hi == 0) { sRedE[0][rt][lo] = s1; sRedE[1][rt][lo] = s2; }
  }
  __syncthreads();
  if (wv < 4) {
    float s1t = sRedE[0][0][lo]+sRedE[0][1][lo]+sRedE[0][2][lo]+sRedE[0][3][lo];
    float s2t = sRedE[1][0][lo]+sRedE[1][1][lo]+sRedE[1][2][lo]+sRedE[1][3][lo];
    float mu = s1t*(1.f/128.f);
    float rs = rsqrtf(s2t*(1.f/128.f) - mu*mu + EPSF);
#pragma unroll
    for (int r = 0; r < 16; ++r) {
      int o = 32*rt + (r&3) + 8*(r>>2) + 4*hi;
      out[((size_t)b*128 + o)*QQ + q0 + lo] = (z2v[r]-mu)*rs*post_g[o] + post_b[o];
    }
  }
}

extern "C" void kernel_launch(void* const* d_in, const int* in_sizes, int n_in,
                              void* d_out, int out_size, void* d_ws, size_t ws_size,
                              hipStream_t stream) {
  const float* x           = (const float*)d_in[0];
  const float* feature     = (const float*)d_in[1];
  const float* I_inv       = (const float*)d_in[2];
  const float* E_inv       = (const float*)d_in[3];
  const float* bev_grid    = (const float*)d_in[4];
  const float* image_plane = (const float*)d_in[5];
  const float* fl_bn_g = (const float*)d_in[6];
  const float* fl_bn_b = (const float*)d_in[7];
  const float* fl_bn_m = (const float*)d_in[8];
  const float* fl_bn_v = (const float*)d_in[9];
  const float* fl_w    = (const float*)d_in[10];
  const float* fp_bn_g = (const float*)d_in[11];
  const float* fp_bn_b = (const float*)d_in[12];
  const float* fp_bn_m = (const float*)d_in[13];
  const float* fp_bn_v = (const float*)d_in[14];
  const float* fp_w    = (const float*)d_in[15];
  const float* bev_w   = (const float*)d_in[16];
  const float* bev_b   = (const float*)d_in[17];
  const float* img_w   = (const float*)d_in[18];
  const float* cam_w   = (const float*)d_in[19];
  const float* q_ln_g  = (const float*)d_in[20];
  const float* q_ln_b  = (const float*)d_in[21];
  const float* q_w     = (const float*)d_in[22];
  const float* q_b     = (const float*)d_in[23];
  const float* k_ln_g  = (const float*)d_in[24];
  const float* k_ln_b  = (const float*)d_in[25];
  const float* k_w     = (const float*)d_in[26];
  const float* k_b     = (const float*)d_in[27];
  const float* v_ln_g  = (const float*)d_in[28];
  const float* v_ln_b  = (const float*)d_in[29];
  const float* v_w     = (const float*)d_in[30];
  const float* v_b     = (const float*)d_in[31];
  const float* proj_w  = (const float*)d_in[32];
  const float* proj_b  = (const float*)d_in[33];
  const float* pre_g   = (const float*)d_in[34];
  const float* pre_b   = (const float*)d_in[35];
  const float* mlp_w1  = (const float*)d_in[36];
  const float* mlp_b1  = (const float*)d_in[37];
  const float* mlp_w2  = (const float*)d_in[38];
  const float* mlp_b2  = (const float*)d_in[39];
  const float* post_g  = (const float*)d_in[40];
  const float* post_b  = (const float*)d_in[41];

  // ws layout: f32 first, then bf16 (all 16B aligned)
  float* ws = (float*)d_ws;
  float* c_embed = ws;                                         // 1536 f32
  float* lsum = ws + 1536;                                     // 2*4*24*1024 f32
  unsigned short* pacb = (unsigned short*)(lsum + (size_t)BB*4*NPART*QQ);
  unsigned short* qhb = pacb + (size_t)BB*4*NPART*QQ*32;       // bf16
  unsigned short* khb = qhb + (size_t)BB*NN*QQ*128;
  unsigned short* vtb = khb + (size_t)BB*NN*KPIX*128;
  unsigned short* wpk = vtb + (size_t)BB*NN*KPIX*128;          // WPK_ELEMS bf16
  float* out = (float*)d_out;

  hipLaunchKernelGGL(prepack_kernel, dim3(1280), dim3(128), 0, stream,
                     fp_w, fl_w, k_w, v_w, q_w, proj_w, mlp_w1, mlp_w2, wpk);
  hipLaunchKernelGGL(ce_kernel, dim3(BB*NN), dim3(128), 0, stream, cam_w, E_inv, c_embed);
  hipLaunchKernelGGL(kv_kernel, dim3(BB*NN*NTILE_KV), dim3(256), 0, stream,
                     feature, I_inv, E_inv, image_plane, c_embed, img_w,
                     fp_bn_g, fp_bn_b, fp_bn_m, fp_bn_v,
                     fl_bn_g, fl_bn_b, fl_bn_m, fl_bn_v,
                     k_ln_g, k_ln_b, k_b,
                     v_ln_g, v_ln_b, v_b,
                     wpk, khb, vtb);
  hipLaunchKernelGGL(q_kernel, dim3(BB*NN*32), dim3(256), 0, stream,
                     x, bev_grid, bev_w, bev_b, c_embed,
                     q_ln_g, q_ln_b, q_b, wpk, qhb);
  hipLaunchKernelGGL(attn_kernel, dim3(BB*16*NN*SPLIT), dim3(256), 0, stream,
                     qhb, khb, vtb, lsum, pacb);
  hipLaunchKernelGGL(epi_kernel, dim3(BB*32), dim3(512), 0, stream,
                     lsum, pacb, x, wpk, proj_b, pre_g, pre_b,
                     mlp_b1, mlp_b2, post_g, post_b, out);
}